// Round 17
// baseline (215.289 us; speedup 1.0000x reference)
//
#include <hip/hip_runtime.h>
#include <cmath>

#define H 8
#define SEQ 2048
#define EDIM 512
#define HD 64
#define EPSF 1e-15f

typedef short bf16x8 __attribute__((ext_vector_type(8)));
typedef float f32x4 __attribute__((ext_vector_type(4)));

// workspace layout (float offsets; 16B-aligned)
#define ZN_OFF    16                                // 3*EDIM
#define STATS_OFF (ZN_OFF + 3 * EDIM)               // 3*H*SEQ fp32 (rounded q2/k2/v2)
#define CQ_OFF    (STATS_OFF + 3 * H * SEQ)         // H*SEQ: 2/(1-q2)
#define IK_OFF    (CQ_OFF + H * SEQ)                // H*SEQ: 1/(1-k2)
#define U16_OFF   (IK_OFF + H * SEQ + 16)
#define WT_U16    0
#define QKVB_U16  (WT_U16 + 3 * EDIM * EDIM)
#define VT_U16    (QKVB_U16 + 3 * SEQ * EDIM)
#define U16_TOTAL (VT_U16 + H * 80 * SEQ)
#define BIG_OFF   (U16_OFF + U16_TOTAL / 2 + 16)    // part (42MB) or ACC (5.2MB) region
#define PART_FLOATS (8 * 32 * 8 * 4 * 320 * 4)      // 10,485,760 floats
#define ACC_FLOATS  (H * SEQ * 80)

__device__ __forceinline__ float bf2f(unsigned short u){
  union { unsigned int i; float f; } v; v.i = ((unsigned int)u) << 16; return v.f;
}
__device__ __forceinline__ unsigned short f2bf(float f){
  union { float f; unsigned int i; } v; v.f = f;
  unsigned int x = v.i;
  unsigned int r = (x + 0x7fffu + ((x >> 16) & 1u)) >> 16;
  return (unsigned short)r;
}

// inline dtype detect: bf16-interpret first 256 u16 of query; fp32 data decodes
// to huge magnitudes w.p. ~1. Butterfly max -> wave-uniform result, no dispatch.
__device__ __forceinline__ int detect_f32(const unsigned short* __restrict__ q){
  const int l = threadIdx.x & 63;
  float mx = 0.f;
  #pragma unroll
  for (int j = 0; j < 4; ++j) mx = fmaxf(mx, fabsf(bf2f(q[l * 4 + j])));
  #pragma unroll
  for (int m = 32; m >= 1; m >>= 1) mx = fmaxf(mx, __shfl_xor(mx, m, 64));
  return mx > 1000.f;
}

// P1: W -> WT bf16 [p][o][i] (transpose) + fp32 column sumsq into zn (pre-zeroed).
__global__ __launch_bounds__(256) void wcvt_kernel(
    const void* __restrict__ Wq, const void* __restrict__ Wk, const void* __restrict__ Wv,
    const unsigned short* __restrict__ qprobe,
    unsigned short* __restrict__ WT, float* __restrict__ zn)
{
  const int p = blockIdx.y;
  const int bi = blockIdx.x >> 3, bo = blockIdx.x & 7;
  const void* W = (p == 0) ? Wq : ((p == 1) ? Wk : Wv);
  const int t = threadIdx.x;
  const int isf32 = detect_f32(qprobe);
  __shared__ float tile[64][65];

  #pragma unroll
  for (int j = 0; j < 16; ++j){
    int idx = t + 256 * j;
    int il = idx >> 6, ol = idx & 63;
    float val;
    if (isf32) val = ((const float*)W)[(size_t)(bi * 64 + il) * EDIM + bo * 64 + ol];
    else       val = bf2f(((const unsigned short*)W)[(size_t)(bi * 64 + il) * EDIM + bo * 64 + ol]);
    tile[il][ol] = val;
  }
  __syncthreads();
  if (t < 64){
    float s = 0.f;
    #pragma unroll 8
    for (int i = 0; i < 64; ++i){ float v = tile[i][t]; s += v * v; }
    atomicAdd(&zn[p * EDIM + bo * 64 + t], s);
  }
  #pragma unroll
  for (int j = 0; j < 16; ++j){
    int idx = t + 256 * j;
    int ol = idx >> 6, il = idx & 63;
    WT[((size_t)p * EDIM + bo * 64 + ol) * EDIM + bi * 64 + il] = f2bf(tile[il][ol]);
  }
}

// K1: hyperbolic linear via MFMA, 16 rows/block, X conversion fused. (R13/R14 exact)
__global__ __launch_bounds__(256) void hlinear_kernel(
    const void* __restrict__ Xq, const void* __restrict__ Xk, const void* __restrict__ Xv,
    const unsigned short* __restrict__ WT,
    const void* __restrict__ Bq, const void* __restrict__ Bk, const void* __restrict__ Bv,
    const float* __restrict__ znacc,
    unsigned short* __restrict__ qkvb, float* __restrict__ stats,
    float* __restrict__ cqs, float* __restrict__ iks,
    unsigned short* __restrict__ VT)
{
  const int p = blockIdx.y;
  const void* X  = (p == 0) ? Xq : ((p == 1) ? Xk : Xv);
  const void* Bb = (p == 0) ? Bq : ((p == 1) ? Bk : Bv);
  const int r0 = blockIdx.x * 16;
  const int t  = threadIdx.x;
  const int w = t >> 6, lane = t & 63;
  const int col = lane & 15, quad = lane >> 4;
  const int isf32 = detect_f32((const unsigned short*)Xq);

  __shared__ float smem[16 * EDIM];
  __shared__ float sw2[16];

  const unsigned short* WTb = WT + ((size_t)p * EDIM + w * 128 + col) * EDIM;
  const float* Xf = (const float*)X + (size_t)(r0 + col) * EDIM;
  const unsigned short* Xh = (const unsigned short*)X + (size_t)(r0 + col) * EDIM;

  f32x4 acc[8];
  #pragma unroll
  for (int nt = 0; nt < 8; ++nt) acc[nt] = (f32x4){0.f, 0.f, 0.f, 0.f};
  float x2part = 0.f;

  for (int ks = 0; ks < 16; ++ks){
    bf16x8 af;
    if (isf32){
      float4 xa = *(const float4*)&Xf[ks * 32 + quad * 8];
      float4 xb = *(const float4*)&Xf[ks * 32 + quad * 8 + 4];
      float xv[8] = {xa.x, xa.y, xa.z, xa.w, xb.x, xb.y, xb.z, xb.w};
      #pragma unroll
      for (int j = 0; j < 8; ++j){ af[j] = (short)f2bf(xv[j]); x2part += xv[j] * xv[j]; }
    } else {
      af = *(const bf16x8*)&Xh[ks * 32 + quad * 8];
      #pragma unroll
      for (int j = 0; j < 8; ++j){ float xv = bf2f((unsigned short)af[j]); x2part += xv * xv; }
    }
    #pragma unroll
    for (int nt = 0; nt < 8; ++nt){
      bf16x8 bf = *(const bf16x8*)&WTb[(size_t)nt * 16 * EDIM + ks * 32 + quad * 8];
      acc[nt] = __builtin_amdgcn_mfma_f32_16x16x32_bf16(af, bf, acc[nt], 0, 0, 0);
    }
  }
  x2part += __shfl_xor(x2part, 16, 64);
  x2part += __shfl_xor(x2part, 32, 64);
  float lamr[4], lm1[4];
  #pragma unroll
  for (int r = 0; r < 4; ++r){
    float x2r = __shfl(x2part, quad * 4 + r, 64);
    lamr[r] = 2.f / (1.f - x2r);
    lm1[r] = lamr[r] - 1.f;
  }
  #pragma unroll
  for (int nt = 0; nt < 8; ++nt){
    const int n = w * 128 + nt * 16 + col;
    float znv = fmaxf(sqrtf(znacc[p * EDIM + n]), EPSF);
    float rb;
    if (isf32) rb = ((const float*)Bb)[n];
    else       rb = bf2f(((const unsigned short*)Bb)[n]);
    float e2r = __expf(2.f * rb);
    float ie2r = 1.f / e2r;
    float ch = 0.5f * (e2r + ie2r), sh = 0.5f * (e2r - ie2r);
    float izn = 1.f / znv;
    float tz = 2.f * znv;
    #pragma unroll
    for (int r = 0; r < 4; ++r){
      float a = (acc[nt][r] * lamr[r] * izn) * ch - lm1[r] * sh;
      float b = a + sqrtf(a * a + 1.f);
      float tt = __expf(tz * __logf(b));
      smem[(quad * 4 + r) * EDIM + n] = 0.5f * (tt - 1.f / tt);
    }
  }
  __syncthreads();

  {
    int row = t >> 4, l = t & 15;
    float s = 0.f;
    for (int o = l; o < EDIM; o += 16){ float wv = smem[row * EDIM + o]; s += wv * wv; }
    #pragma unroll
    for (int m = 8; m >= 1; m >>= 1) s += __shfl_xor(s, m, 16);
    if (l == 0) sw2[row] = s;
  }
  __syncthreads();

  const int o0 = 2 * t;
  const int h0 = t >> 5;
  const int d0 = o0 & 63;
  const int l5 = t & 31;
  #pragma unroll
  for (int rr = 0; rr < 16; ++rr){
    float inv = 1.f / (1.f + sqrtf(1.f + sw2[rr]));
    unsigned short b0 = f2bf(smem[rr * EDIM + o0] * inv);
    unsigned short b1 = f2bf(smem[rr * EDIM + o0 + 1] * inv);
    float r0v = bf2f(b0), r1v = bf2f(b1);
    int s = r0 + rr;
    unsigned int* dst = (unsigned int*)&qkvb[(((size_t)p * H + h0) * SEQ + s) * HD + d0];
    *dst = (unsigned int)b0 | ((unsigned int)b1 << 16);
    float ss = r0v * r0v + r1v * r1v;
    #pragma unroll
    for (int m = 16; m >= 1; m >>= 1) ss += __shfl_xor(ss, m, 64);
    if (p == 2){
      float lam = 2.f / (1.f - ss);
      VT[((size_t)h0 * 80 + d0) * SEQ + s]     = f2bf(r0v * lam);
      VT[((size_t)h0 * 80 + d0 + 1) * SEQ + s] = f2bf(r1v * lam);
      if (l5 < 16)
        VT[((size_t)h0 * 80 + 64 + l5) * SEQ + s] = (l5 == 0) ? f2bf(lam - 1.f) : 0;
    }
    if (l5 == 0){
      stats[((size_t)p * H + h0) * SEQ + s] = ss;
      if (p == 0) cqs[(size_t)h0 * SEQ + s] = 2.f / (1.f - ss);
      if (p == 1) iks[(size_t)h0 * SEQ + s] = 1.f / (1.f - ss);
    }
  }
}

// K3a: attention — R16 pipelined body. Epilogue: if use_part, plain coalesced
// float4 partial stores to part[h][tile][sl][w] (no RMW, no collisions);
// else fallback atomicAdd into ACC (R16 path, for small ws).
__global__ __launch_bounds__(256) void attn_kernel(
    const unsigned short* __restrict__ Qb, const unsigned short* __restrict__ Kb,
    const unsigned short* __restrict__ VT,
    const float* __restrict__ q2s_all, const float* __restrict__ k2s_all,
    const float* __restrict__ cqs_all, const float* __restrict__ iks_all,
    const void* __restrict__ tau, const void* __restrict__ gam,
    const unsigned short* __restrict__ qprobe,
    float* __restrict__ big, int use_part)
{
  const int h  = blockIdx.y;
  const int tile = blockIdx.x >> 3;      // 64-q supertile 0..31
  const int sl = blockIdx.x & 7;         // k-slice
  if (sl > tile) return;
  const int t = threadIdx.x;
  const int w = t >> 6, lane = t & 63;
  const int col = lane & 15, quad = lane >> 4;
  const int q0 = tile * 64 + w * 16;

  const unsigned short* Qh  = Qb + (size_t)h * SEQ * HD;
  const unsigned short* Kh  = Kb + (size_t)h * SEQ * HD;
  const unsigned short* VTh = VT + (size_t)h * 80 * SEQ;
  const float* q2s = q2s_all + (size_t)h * SEQ;
  const float* k2s = k2s_all + (size_t)h * SEQ;
  const float* cqs = cqs_all + (size_t)h * SEQ;
  const float* iks = iks_all + (size_t)h * SEQ;

  const int isf32 = detect_f32(qprobe);
  float tauv, gamv;
  if (isf32){ tauv = ((const float*)tau)[0]; gamv = ((const float*)gam)[0]; }
  else      { tauv = bf2f(((const unsigned short*)tau)[0]);
              gamv = bf2f(((const unsigned short*)gam)[0]); }
  const float e_tau = __expf(tauv);

  const int srcA = ((quad & 1) * 2) * 16 + col;
  const int srcB = srcA + 16;
  const int tsel = quad >> 1;

  bf16x8 qf0 = *(const bf16x8*)&Qh[(size_t)(q0 + col) * HD + quad * 8];
  bf16x8 qf1 = *(const bf16x8*)&Qh[(size_t)(q0 + col) * HD + 32 + quad * 8];
  const float q2 = q2s[q0 + col];
  const float cq = cqs[q0 + col];
  const int qmax = q0 + col;

  f32x4 pv[5];
  #pragma unroll
  for (int nt = 0; nt < 5; ++nt) pv[nt] = (f32x4){0.f, 0.f, 0.f, 0.f};

  const int nch = ((tile - sl) >> 3) + 1;   // chunks: sl, sl+8, ..., <= tile
  const int nhalf = nch * 2;
  int kb32 = sl * 64;

  bf16x8 ckf0[2], ckf1[2], nkf0[2], nkf1[2];
  float4 ck2[2], cik[2], nk2[2], nik[2];
  #pragma unroll
  for (int tt = 0; tt < 2; ++tt){
    const int kbase = kb32 + 16 * tt;
    ckf0[tt] = *(const bf16x8*)&Kh[(size_t)(kbase + col) * HD + quad * 8];
    ckf1[tt] = *(const bf16x8*)&Kh[(size_t)(kbase + col) * HD + 32 + quad * 8];
    ck2[tt]  = *(const float4*)&k2s[kbase + quad * 4];
    cik[tt]  = *(const float4*)&iks[kbase + quad * 4];
  }

  for (int i = 0; i < nhalf; ++i){
    const int nkb32 = (i & 1) ? (kb32 + 512 - 32) : (kb32 + 32);
    const bool have_next = (i + 1 < nhalf);
    if (have_next){
      #pragma unroll
      for (int tt = 0; tt < 2; ++tt){
        const int kbase = nkb32 + 16 * tt;
        nkf0[tt] = *(const bf16x8*)&Kh[(size_t)(kbase + col) * HD + quad * 8];
        nkf1[tt] = *(const bf16x8*)&Kh[(size_t)(kbase + col) * HD + 32 + quad * 8];
        nk2[tt]  = *(const float4*)&k2s[kbase + quad * 4];
        nik[tt]  = *(const float4*)&iks[kbase + quad * 4];
      }
    }

    unsigned int tlo[2], thi[2];
    #pragma unroll
    for (int tt = 0; tt < 2; ++tt){
      const int kbase = kb32 + 16 * tt;
      f32x4 s = (f32x4){0.f, 0.f, 0.f, 0.f};
      s = __builtin_amdgcn_mfma_f32_16x16x32_bf16(ckf0[tt], qf0, s, 0, 0, 0);
      s = __builtin_amdgcn_mfma_f32_16x16x32_bf16(ckf1[tt], qf1, s, 0, 0, 0);
      unsigned short pb[4];
      #pragma unroll
      for (int r = 0; r < 4; ++r){
        float k2 = (r == 0) ? ck2[tt].x : (r == 1) ? ck2[tt].y : (r == 2) ? ck2[tt].z : ck2[tt].w;
        float ik = (r == 0) ? cik[tt].x : (r == 1) ? cik[tt].y : (r == 2) ? cik[tt].z : cik[tt].w;
        float diff2 = fmaxf(q2 + k2 - 2.f * s[r], 0.f);
        float u = fmaxf(diff2 * cq * ik, 1e-7f);
        float z = 1.f + u + sqrtf(u * (u + 2.f));
        float dist = __logf(z);
        float wv = __expf(-e_tau * dist - gamv);
        int key = kbase + quad * 4 + r;
        if (key > qmax) wv = 0.f;
        pb[r] = f2bf(wv);
      }
      tlo[tt] = (unsigned int)pb[0] | ((unsigned int)pb[1] << 16);
      thi[tt] = (unsigned int)pb[2] | ((unsigned int)pb[3] << 16);
    }
    unsigned int a0 = (unsigned int)__shfl((int)tlo[0], srcA, 64);
    unsigned int a1 = (unsigned int)__shfl((int)tlo[1], srcA, 64);
    unsigned int b0 = (unsigned int)__shfl((int)thi[0], srcA, 64);
    unsigned int b1 = (unsigned int)__shfl((int)thi[1], srcA, 64);
    unsigned int c0 = (unsigned int)__shfl((int)tlo[0], srcB, 64);
    unsigned int c1 = (unsigned int)__shfl((int)tlo[1], srcB, 64);
    unsigned int d0 = (unsigned int)__shfl((int)thi[0], srcB, 64);
    unsigned int d1 = (unsigned int)__shfl((int)thi[1], srcB, 64);
    union { uint4 u; bf16x8 v; } pw;
    pw.u.x = tsel ? a1 : a0;
    pw.u.y = tsel ? b1 : b0;
    pw.u.z = tsel ? c1 : c0;
    pw.u.w = tsel ? d1 : d0;
    #pragma unroll
    for (int nt = 0; nt < 5; ++nt){
      bf16x8 vf = *(const bf16x8*)&VTh[(size_t)(16 * nt + col) * SEQ + kb32 + quad * 8];
      pv[nt] = __builtin_amdgcn_mfma_f32_16x16x32_bf16(pw.v, vf, pv[nt], 0, 0, 0);
    }

    if (have_next){
      #pragma unroll
      for (int tt = 0; tt < 2; ++tt){
        ckf0[tt] = nkf0[tt]; ckf1[tt] = nkf1[tt];
        ck2[tt] = nk2[tt];   cik[tt] = nik[tt];
      }
    }
    kb32 = nkb32;
  }

  if (use_part){
    // slot = part[h][tile][sl][w]: 64 lanes x 5 float4, fully coalesced stores
    float4* slot = (float4*)big +
        (size_t)(((((h * 32 + tile) * 8) + sl) * 4 + w)) * 320;
    #pragma unroll
    for (int nt = 0; nt < 5; ++nt)
      slot[nt * 64 + lane] = (float4){pv[nt][0], pv[nt][1], pv[nt][2], pv[nt][3]};
  } else {
    #pragma unroll
    for (int r = 0; r < 4; ++r){
      float* row = big + ((size_t)h * SEQ + q0 + quad * 4 + r) * 80;
      #pragma unroll
      for (int nt = 0; nt < 5; ++nt)
        atomicAdd(&row[16 * nt + col], pv[nt][r]);
    }
  }
}

// K3b: sum valid slices (or read ACC) + gyromidpoint epilogue. Grid (128, H), 64 thr.
__global__ __launch_bounds__(64) void attn_fin_kernel(
    const float* __restrict__ big, int use_part,
    float* __restrict__ out, float beta_scale)
{
  const int h = blockIdx.y, tile16 = blockIdx.x;
  const int t = threadIdx.x;
  const int col = t & 15, quad = t >> 4;
  const int q0 = tile16 * 16;

  f32x4 pv[5];
  #pragma unroll
  for (int nt = 0; nt < 5; ++nt) pv[nt] = (f32x4){0.f, 0.f, 0.f, 0.f};

  if (use_part){
    const int st = tile16 >> 2, w = tile16 & 3;
    const int nv = (st + 1 < 8) ? st + 1 : 8;
    for (int sl = 0; sl < nv; ++sl){
      const float4* slot = (const float4*)big +
          (size_t)(((((h * 32 + st) * 8) + sl) * 4 + w)) * 320;
      #pragma unroll
      for (int nt = 0; nt < 5; ++nt){
        float4 v = slot[nt * 64 + t];
        pv[nt][0] += v.x; pv[nt][1] += v.y; pv[nt][2] += v.z; pv[nt][3] += v.w;
      }
    }
  } else {
    #pragma unroll
    for (int nt = 0; nt < 5; ++nt)
      #pragma unroll
      for (int r = 0; r < 4; ++r)
        pv[nt][r] = big[((size_t)h * SEQ + q0 + quad * 4 + r) * 80 + 16 * nt + col];
  }

  #pragma unroll
  for (int r = 0; r < 4; ++r){
    float den = __shfl(pv[4][r], quad * 16, 64);
    den = fmaxf(den, EPSF);
    float inv_den = 1.f / den;
    float g[4];
    float gsq = 0.f;
    #pragma unroll
    for (int nt = 0; nt < 4; ++nt){ g[nt] = pv[nt][r] * inv_den; gsq += g[nt] * g[nt]; }
    #pragma unroll
    for (int m = 8; m >= 1; m >>= 1) gsq += __shfl_xor(gsq, m, 64);
    float gn = fmaxf(sqrtf(gsq), EPSF);
    float x = fminf(gn, 1.f - 1e-7f);
    float tt2 = x / (1.f + sqrtf(1.f - x * x));
    float scl = (tt2 / gn) * beta_scale;
    const int q = q0 + quad * 4 + r;
    #pragma unroll
    for (int nt = 0; nt < 4; ++nt)
      out[(size_t)q * EDIM + h * HD + 16 * nt + col] = g[nt] * scl;
  }
}

extern "C" void kernel_launch(void* const* d_in, const int* in_sizes, int n_in,
                              void* d_out, int out_size, void* d_ws, size_t ws_size,
                              hipStream_t stream){
  const void* Xq  = d_in[0];
  const void* Xk  = d_in[1];
  const void* Xv  = d_in[2];
  const void* Wq  = d_in[3];
  const void* Wk  = d_in[4];
  const void* Wv  = d_in[5];
  const void* Bq  = d_in[6];
  const void* Bk  = d_in[7];
  const void* Bv  = d_in[8];
  const void* tau = d_in[9];
  const void* gam = d_in[10];

  float* wsf   = (float*)d_ws;
  float* zn    = wsf + ZN_OFF;
  float* stats = wsf + STATS_OFF;
  float* cqs   = wsf + CQ_OFF;
  float* iks   = wsf + IK_OFF;
  unsigned short* u16b = (unsigned short*)(wsf + U16_OFF);
  unsigned short* WT   = u16b + WT_U16;
  unsigned short* qkvb = u16b + QKVB_U16;
  unsigned short* VT   = u16b + VT_U16;
  float* big   = wsf + BIG_OFF;

  const int use_part = (ws_size >= (size_t)(BIG_OFF + PART_FLOATS) * sizeof(float)) ? 1 : 0;

  unsigned short* Qb = qkvb;
  unsigned short* Kb = qkvb + (size_t)H * SEQ * HD;
  float* q2s = stats;
  float* k2s = stats + (size_t)H * SEQ;
  const unsigned short* qprobe = (const unsigned short*)Xq;

  double lb1 = lgamma(EDIM / 2.0) + lgamma(0.5) - lgamma(EDIM / 2.0 + 0.5);
  double lb2 = lgamma(HD / 2.0)   + lgamma(0.5) - lgamma(HD / 2.0 + 0.5);
  float beta_scale = (float)exp(lb1 - lb2);

  hipMemsetAsync(zn, 0, (size_t)(3 * EDIM) * sizeof(float), stream);
  if (!use_part)
    hipMemsetAsync(big, 0, (size_t)ACC_FLOATS * sizeof(float), stream);
  wcvt_kernel<<<dim3(64, 3), dim3(256), 0, stream>>>(Wq, Wk, Wv, qprobe, WT, zn);
  hlinear_kernel<<<dim3(SEQ / 16, 3), dim3(256), 0, stream>>>(
      Xq, Xk, Xv, WT, Bq, Bk, Bv, zn, qkvb, stats, cqs, iks, VT);
  attn_kernel<<<dim3(32 * 8, H), dim3(256), 0, stream>>>(
      Qb, Kb, VT, q2s, k2s, cqs, iks, tau, gam, qprobe, big, use_part);
  attn_fin_kernel<<<dim3(128, H), dim3(64), 0, stream>>>(
      big, use_part, (float*)d_out, beta_scale);
}

// Round 18
// 214.790 us; speedup vs baseline: 1.0023x; 1.0023x over previous
//
#include <hip/hip_runtime.h>
#include <cmath>

#define H 8
#define SEQ 2048
#define EDIM 512
#define HD 64
#define EPSF 1e-15f

typedef short bf16x8 __attribute__((ext_vector_type(8)));
typedef float f32x4 __attribute__((ext_vector_type(4)));

// workspace layout (float offsets; 16B-aligned)
#define ZN_OFF    16                                // 3*EDIM
#define STATS_OFF (ZN_OFF + 3 * EDIM)               // 3*H*SEQ fp32 (rounded q2/k2/v2)
#define CQ_OFF    (STATS_OFF + 3 * H * SEQ)         // H*SEQ: 2/(1-q2)
#define IK_OFF    (CQ_OFF + H * SEQ)                // H*SEQ: 1/(1-k2)
#define U16_OFF   (IK_OFF + H * SEQ + 16)
#define WT_U16    0
#define QKVB_U16  (WT_U16 + 3 * EDIM * EDIM)
#define VT_U16    (QKVB_U16 + 3 * SEQ * EDIM)
#define U16_TOTAL (VT_U16 + H * 80 * SEQ)
#define BIG_OFF   (U16_OFF + U16_TOTAL / 2 + 16)    // part (42MB) or ACC (5.2MB) region
#define PART_FLOATS (8 * 32 * 8 * 4 * 320 * 4)      // 10,485,760 floats
#define ACC_FLOATS  (H * SEQ * 80)

__device__ __forceinline__ float bf2f(unsigned short u){
  union { unsigned int i; float f; } v; v.i = ((unsigned int)u) << 16; return v.f;
}
__device__ __forceinline__ unsigned short f2bf(float f){
  union { float f; unsigned int i; } v; v.f = f;
  unsigned int x = v.i;
  unsigned int r = (x + 0x7fffu + ((x >> 16) & 1u)) >> 16;
  return (unsigned short)r;
}

// inline dtype detect: bf16-interpret first 256 u16 of query; fp32 data decodes
// to huge magnitudes w.p. ~1. Butterfly max -> wave-uniform result, no dispatch.
__device__ __forceinline__ int detect_f32(const unsigned short* __restrict__ q){
  const int l = threadIdx.x & 63;
  float mx = 0.f;
  #pragma unroll
  for (int j = 0; j < 4; ++j) mx = fmaxf(mx, fabsf(bf2f(q[l * 4 + j])));
  #pragma unroll
  for (int m = 32; m >= 1; m >>= 1) mx = fmaxf(mx, __shfl_xor(mx, m, 64));
  return mx > 1000.f;
}

// P1: W -> WT bf16 [p][o][i] (transpose) + fp32 column sumsq into zn (pre-zeroed).
__global__ __launch_bounds__(256) void wcvt_kernel(
    const void* __restrict__ Wq, const void* __restrict__ Wk, const void* __restrict__ Wv,
    const unsigned short* __restrict__ qprobe,
    unsigned short* __restrict__ WT, float* __restrict__ zn)
{
  const int p = blockIdx.y;
  const int bi = blockIdx.x >> 3, bo = blockIdx.x & 7;
  const void* W = (p == 0) ? Wq : ((p == 1) ? Wk : Wv);
  const int t = threadIdx.x;
  const int isf32 = detect_f32(qprobe);
  __shared__ float tile[64][65];

  #pragma unroll
  for (int j = 0; j < 16; ++j){
    int idx = t + 256 * j;
    int il = idx >> 6, ol = idx & 63;
    float val;
    if (isf32) val = ((const float*)W)[(size_t)(bi * 64 + il) * EDIM + bo * 64 + ol];
    else       val = bf2f(((const unsigned short*)W)[(size_t)(bi * 64 + il) * EDIM + bo * 64 + ol]);
    tile[il][ol] = val;
  }
  __syncthreads();
  if (t < 64){
    float s = 0.f;
    #pragma unroll 8
    for (int i = 0; i < 64; ++i){ float v = tile[i][t]; s += v * v; }
    atomicAdd(&zn[p * EDIM + bo * 64 + t], s);
  }
  #pragma unroll
  for (int j = 0; j < 16; ++j){
    int idx = t + 256 * j;
    int ol = idx >> 6, il = idx & 63;
    WT[((size_t)p * EDIM + bo * 64 + ol) * EDIM + bi * 64 + il] = f2bf(tile[il][ol]);
  }
}

// K1: hyperbolic linear via MFMA, 16 rows/block, X conversion fused, with an
// explicit register double-buffer on the ks loop (A + 8 B frags one iter ahead).
__global__ __launch_bounds__(256) void hlinear_kernel(
    const void* __restrict__ Xq, const void* __restrict__ Xk, const void* __restrict__ Xv,
    const unsigned short* __restrict__ WT,
    const void* __restrict__ Bq, const void* __restrict__ Bk, const void* __restrict__ Bv,
    const float* __restrict__ znacc,
    unsigned short* __restrict__ qkvb, float* __restrict__ stats,
    float* __restrict__ cqs, float* __restrict__ iks,
    unsigned short* __restrict__ VT)
{
  const int p = blockIdx.y;
  const void* X  = (p == 0) ? Xq : ((p == 1) ? Xk : Xv);
  const void* Bb = (p == 0) ? Bq : ((p == 1) ? Bk : Bv);
  const int r0 = blockIdx.x * 16;
  const int t  = threadIdx.x;
  const int w = t >> 6, lane = t & 63;
  const int col = lane & 15, quad = lane >> 4;
  const int isf32 = detect_f32((const unsigned short*)Xq);

  __shared__ float smem[16 * EDIM];
  __shared__ float sw2[16];

  const unsigned short* WTb = WT + ((size_t)p * EDIM + w * 128 + col) * EDIM;
  const float* Xf = (const float*)X + (size_t)(r0 + col) * EDIM;
  const unsigned short* Xh = (const unsigned short*)X + (size_t)(r0 + col) * EDIM;

  f32x4 acc[8];
  #pragma unroll
  for (int nt = 0; nt < 8; ++nt) acc[nt] = (f32x4){0.f, 0.f, 0.f, 0.f};
  float x2part = 0.f;

  // load helper is inlined manually: load A-frag for iteration ks (+ x2 accumulate)
  bf16x8 caf, naf;
  bf16x8 cbf[8], nbf[8];
  {
    if (isf32){
      float4 xa = *(const float4*)&Xf[quad * 8];
      float4 xb = *(const float4*)&Xf[quad * 8 + 4];
      float xv[8] = {xa.x, xa.y, xa.z, xa.w, xb.x, xb.y, xb.z, xb.w};
      #pragma unroll
      for (int j = 0; j < 8; ++j){ caf[j] = (short)f2bf(xv[j]); x2part += xv[j] * xv[j]; }
    } else {
      caf = *(const bf16x8*)&Xh[quad * 8];
      #pragma unroll
      for (int j = 0; j < 8; ++j){ float xv = bf2f((unsigned short)caf[j]); x2part += xv * xv; }
    }
    #pragma unroll
    for (int nt = 0; nt < 8; ++nt)
      cbf[nt] = *(const bf16x8*)&WTb[(size_t)nt * 16 * EDIM + quad * 8];
  }

  for (int ks = 0; ks < 16; ++ks){
    if (ks + 1 < 16){
      const int off = (ks + 1) * 32 + quad * 8;
      if (isf32){
        float4 xa = *(const float4*)&Xf[off];
        float4 xb = *(const float4*)&Xf[off + 4];
        float xv[8] = {xa.x, xa.y, xa.z, xa.w, xb.x, xb.y, xb.z, xb.w};
        #pragma unroll
        for (int j = 0; j < 8; ++j){ naf[j] = (short)f2bf(xv[j]); x2part += xv[j] * xv[j]; }
      } else {
        naf = *(const bf16x8*)&Xh[off];
        #pragma unroll
        for (int j = 0; j < 8; ++j){ float xv = bf2f((unsigned short)naf[j]); x2part += xv * xv; }
      }
      #pragma unroll
      for (int nt = 0; nt < 8; ++nt)
        nbf[nt] = *(const bf16x8*)&WTb[(size_t)nt * 16 * EDIM + off];
    }
    #pragma unroll
    for (int nt = 0; nt < 8; ++nt)
      acc[nt] = __builtin_amdgcn_mfma_f32_16x16x32_bf16(caf, cbf[nt], acc[nt], 0, 0, 0);
    if (ks + 1 < 16){
      caf = naf;
      #pragma unroll
      for (int nt = 0; nt < 8; ++nt) cbf[nt] = nbf[nt];
    }
  }
  x2part += __shfl_xor(x2part, 16, 64);
  x2part += __shfl_xor(x2part, 32, 64);
  float lamr[4], lm1[4];
  #pragma unroll
  for (int r = 0; r < 4; ++r){
    float x2r = __shfl(x2part, quad * 4 + r, 64);
    lamr[r] = 2.f / (1.f - x2r);
    lm1[r] = lamr[r] - 1.f;
  }
  #pragma unroll
  for (int nt = 0; nt < 8; ++nt){
    const int n = w * 128 + nt * 16 + col;
    float znv = fmaxf(sqrtf(znacc[p * EDIM + n]), EPSF);
    float rb;
    if (isf32) rb = ((const float*)Bb)[n];
    else       rb = bf2f(((const unsigned short*)Bb)[n]);
    float e2r = __expf(2.f * rb);
    float ie2r = 1.f / e2r;
    float ch = 0.5f * (e2r + ie2r), sh = 0.5f * (e2r - ie2r);
    float izn = 1.f / znv;
    float tz = 2.f * znv;
    #pragma unroll
    for (int r = 0; r < 4; ++r){
      float a = (acc[nt][r] * lamr[r] * izn) * ch - lm1[r] * sh;
      float b = a + sqrtf(a * a + 1.f);
      float tt = __expf(tz * __logf(b));
      smem[(quad * 4 + r) * EDIM + n] = 0.5f * (tt - 1.f / tt);
    }
  }
  __syncthreads();

  {
    int row = t >> 4, l = t & 15;
    float s = 0.f;
    for (int o = l; o < EDIM; o += 16){ float wv = smem[row * EDIM + o]; s += wv * wv; }
    #pragma unroll
    for (int m = 8; m >= 1; m >>= 1) s += __shfl_xor(s, m, 16);
    if (l == 0) sw2[row] = s;
  }
  __syncthreads();

  const int o0 = 2 * t;
  const int h0 = t >> 5;
  const int d0 = o0 & 63;
  const int l5 = t & 31;
  #pragma unroll
  for (int rr = 0; rr < 16; ++rr){
    float inv = 1.f / (1.f + sqrtf(1.f + sw2[rr]));
    unsigned short b0 = f2bf(smem[rr * EDIM + o0] * inv);
    unsigned short b1 = f2bf(smem[rr * EDIM + o0 + 1] * inv);
    float r0v = bf2f(b0), r1v = bf2f(b1);
    int s = r0 + rr;
    unsigned int* dst = (unsigned int*)&qkvb[(((size_t)p * H + h0) * SEQ + s) * HD + d0];
    *dst = (unsigned int)b0 | ((unsigned int)b1 << 16);
    float ss = r0v * r0v + r1v * r1v;
    #pragma unroll
    for (int m = 16; m >= 1; m >>= 1) ss += __shfl_xor(ss, m, 64);
    if (p == 2){
      float lam = 2.f / (1.f - ss);
      VT[((size_t)h0 * 80 + d0) * SEQ + s]     = f2bf(r0v * lam);
      VT[((size_t)h0 * 80 + d0 + 1) * SEQ + s] = f2bf(r1v * lam);
      if (l5 < 16)
        VT[((size_t)h0 * 80 + 64 + l5) * SEQ + s] = (l5 == 0) ? f2bf(lam - 1.f) : 0;
    }
    if (l5 == 0){
      stats[((size_t)p * H + h0) * SEQ + s] = ss;
      if (p == 0) cqs[(size_t)h0 * SEQ + s] = 2.f / (1.f - ss);
      if (p == 1) iks[(size_t)h0 * SEQ + s] = 1.f / (1.f - ss);
    }
  }
}

// K3a: attention — R16/R17 pipelined body, frozen (best measured: 68us).
__global__ __launch_bounds__(256) void attn_kernel(
    const unsigned short* __restrict__ Qb, const unsigned short* __restrict__ Kb,
    const unsigned short* __restrict__ VT,
    const float* __restrict__ q2s_all, const float* __restrict__ k2s_all,
    const float* __restrict__ cqs_all, const float* __restrict__ iks_all,
    const void* __restrict__ tau, const void* __restrict__ gam,
    const unsigned short* __restrict__ qprobe,
    float* __restrict__ big, int use_part)
{
  const int h  = blockIdx.y;
  const int tile = blockIdx.x >> 3;
  const int sl = blockIdx.x & 7;
  if (sl > tile) return;
  const int t = threadIdx.x;
  const int w = t >> 6, lane = t & 63;
  const int col = lane & 15, quad = lane >> 4;
  const int q0 = tile * 64 + w * 16;

  const unsigned short* Qh  = Qb + (size_t)h * SEQ * HD;
  const unsigned short* Kh  = Kb + (size_t)h * SEQ * HD;
  const unsigned short* VTh = VT + (size_t)h * 80 * SEQ;
  const float* q2s = q2s_all + (size_t)h * SEQ;
  const float* k2s = k2s_all + (size_t)h * SEQ;
  const float* cqs = cqs_all + (size_t)h * SEQ;
  const float* iks = iks_all + (size_t)h * SEQ;

  const int isf32 = detect_f32(qprobe);
  float tauv, gamv;
  if (isf32){ tauv = ((const float*)tau)[0]; gamv = ((const float*)gam)[0]; }
  else      { tauv = bf2f(((const unsigned short*)tau)[0]);
              gamv = bf2f(((const unsigned short*)gam)[0]); }
  const float e_tau = __expf(tauv);

  const int srcA = ((quad & 1) * 2) * 16 + col;
  const int srcB = srcA + 16;
  const int tsel = quad >> 1;

  bf16x8 qf0 = *(const bf16x8*)&Qh[(size_t)(q0 + col) * HD + quad * 8];
  bf16x8 qf1 = *(const bf16x8*)&Qh[(size_t)(q0 + col) * HD + 32 + quad * 8];
  const float q2 = q2s[q0 + col];
  const float cq = cqs[q0 + col];
  const int qmax = q0 + col;

  f32x4 pv[5];
  #pragma unroll
  for (int nt = 0; nt < 5; ++nt) pv[nt] = (f32x4){0.f, 0.f, 0.f, 0.f};

  const int nch = ((tile - sl) >> 3) + 1;
  const int nhalf = nch * 2;
  int kb32 = sl * 64;

  bf16x8 ckf0[2], ckf1[2], nkf0[2], nkf1[2];
  float4 ck2[2], cik[2], nk2[2], nik[2];
  #pragma unroll
  for (int tt = 0; tt < 2; ++tt){
    const int kbase = kb32 + 16 * tt;
    ckf0[tt] = *(const bf16x8*)&Kh[(size_t)(kbase + col) * HD + quad * 8];
    ckf1[tt] = *(const bf16x8*)&Kh[(size_t)(kbase + col) * HD + 32 + quad * 8];
    ck2[tt]  = *(const float4*)&k2s[kbase + quad * 4];
    cik[tt]  = *(const float4*)&iks[kbase + quad * 4];
  }

  for (int i = 0; i < nhalf; ++i){
    const int nkb32 = (i & 1) ? (kb32 + 512 - 32) : (kb32 + 32);
    const bool have_next = (i + 1 < nhalf);
    if (have_next){
      #pragma unroll
      for (int tt = 0; tt < 2; ++tt){
        const int kbase = nkb32 + 16 * tt;
        nkf0[tt] = *(const bf16x8*)&Kh[(size_t)(kbase + col) * HD + quad * 8];
        nkf1[tt] = *(const bf16x8*)&Kh[(size_t)(kbase + col) * HD + 32 + quad * 8];
        nk2[tt]  = *(const float4*)&k2s[kbase + quad * 4];
        nik[tt]  = *(const float4*)&iks[kbase + quad * 4];
      }
    }

    unsigned int tlo[2], thi[2];
    #pragma unroll
    for (int tt = 0; tt < 2; ++tt){
      const int kbase = kb32 + 16 * tt;
      f32x4 s = (f32x4){0.f, 0.f, 0.f, 0.f};
      s = __builtin_amdgcn_mfma_f32_16x16x32_bf16(ckf0[tt], qf0, s, 0, 0, 0);
      s = __builtin_amdgcn_mfma_f32_16x16x32_bf16(ckf1[tt], qf1, s, 0, 0, 0);
      unsigned short pb[4];
      #pragma unroll
      for (int r = 0; r < 4; ++r){
        float k2 = (r == 0) ? ck2[tt].x : (r == 1) ? ck2[tt].y : (r == 2) ? ck2[tt].z : ck2[tt].w;
        float ik = (r == 0) ? cik[tt].x : (r == 1) ? cik[tt].y : (r == 2) ? cik[tt].z : cik[tt].w;
        float diff2 = fmaxf(q2 + k2 - 2.f * s[r], 0.f);
        float u = fmaxf(diff2 * cq * ik, 1e-7f);
        float z = 1.f + u + sqrtf(u * (u + 2.f));
        float dist = __logf(z);
        float wv = __expf(-e_tau * dist - gamv);
        int key = kbase + quad * 4 + r;
        if (key > qmax) wv = 0.f;
        pb[r] = f2bf(wv);
      }
      tlo[tt] = (unsigned int)pb[0] | ((unsigned int)pb[1] << 16);
      thi[tt] = (unsigned int)pb[2] | ((unsigned int)pb[3] << 16);
    }
    unsigned int a0 = (unsigned int)__shfl((int)tlo[0], srcA, 64);
    unsigned int a1 = (unsigned int)__shfl((int)tlo[1], srcA, 64);
    unsigned int b0 = (unsigned int)__shfl((int)thi[0], srcA, 64);
    unsigned int b1 = (unsigned int)__shfl((int)thi[1], srcA, 64);
    unsigned int c0 = (unsigned int)__shfl((int)tlo[0], srcB, 64);
    unsigned int c1 = (unsigned int)__shfl((int)tlo[1], srcB, 64);
    unsigned int d0 = (unsigned int)__shfl((int)thi[0], srcB, 64);
    unsigned int d1 = (unsigned int)__shfl((int)thi[1], srcB, 64);
    union { uint4 u; bf16x8 v; } pw;
    pw.u.x = tsel ? a1 : a0;
    pw.u.y = tsel ? b1 : b0;
    pw.u.z = tsel ? c1 : c0;
    pw.u.w = tsel ? d1 : d0;
    #pragma unroll
    for (int nt = 0; nt < 5; ++nt){
      bf16x8 vf = *(const bf16x8*)&VTh[(size_t)(16 * nt + col) * SEQ + kb32 + quad * 8];
      pv[nt] = __builtin_amdgcn_mfma_f32_16x16x32_bf16(pw.v, vf, pv[nt], 0, 0, 0);
    }

    if (have_next){
      #pragma unroll
      for (int tt = 0; tt < 2; ++tt){
        ckf0[tt] = nkf0[tt]; ckf1[tt] = nkf1[tt];
        ck2[tt] = nk2[tt];   cik[tt] = nik[tt];
      }
    }
    kb32 = nkb32;
  }

  if (use_part){
    float4* slot = (float4*)big +
        (size_t)(((((h * 32 + tile) * 8) + sl) * 4 + w)) * 320;
    #pragma unroll
    for (int nt = 0; nt < 5; ++nt)
      slot[nt * 64 + lane] = (float4){pv[nt][0], pv[nt][1], pv[nt][2], pv[nt][3]};
  } else {
    #pragma unroll
    for (int r = 0; r < 4; ++r){
      float* row = big + ((size_t)h * SEQ + q0 + quad * 4 + r) * 80;
      #pragma unroll
      for (int nt = 0; nt < 5; ++nt)
        atomicAdd(&row[16 * nt + col], pv[nt][r]);
    }
  }
}

// K3b: slice-sum (4 waves, <=2 serial reads each) + LDS reduce + gyromidpoint.
// Grid (128, H), 256 threads.
__global__ __launch_bounds__(256) void attn_fin_kernel(
    const float* __restrict__ big, int use_part,
    float* __restrict__ out, float beta_scale)
{
  const int h = blockIdx.y, tile16 = blockIdx.x;
  const int t = threadIdx.x;
  const int w = t >> 6, lane = t & 63;
  const int col = lane & 15, quad = lane >> 4;
  const int q0 = tile16 * 16;

  __shared__ float red[4][64][20];

  f32x4 pv[5];
  #pragma unroll
  for (int nt = 0; nt < 5; ++nt) pv[nt] = (f32x4){0.f, 0.f, 0.f, 0.f};

  if (use_part){
    const int st = tile16 >> 2, wq = tile16 & 3;
    const int nv = (st + 1 < 8) ? st + 1 : 8;
    for (int sl = w; sl < nv; sl += 4){
      const float4* slot = (const float4*)big +
          (size_t)(((((h * 32 + st) * 8) + sl) * 4 + wq)) * 320;
      #pragma unroll
      for (int nt = 0; nt < 5; ++nt){
        float4 v = slot[nt * 64 + lane];
        pv[nt][0] += v.x; pv[nt][1] += v.y; pv[nt][2] += v.z; pv[nt][3] += v.w;
      }
    }
  } else if (w == 0){
    #pragma unroll
    for (int nt = 0; nt < 5; ++nt)
      #pragma unroll
      for (int r = 0; r < 4; ++r)
        pv[nt][r] = big[((size_t)h * SEQ + q0 + quad * 4 + r) * 80 + 16 * nt + col];
  }

  #pragma unroll
  for (int nt = 0; nt < 5; ++nt)
    *(float4*)&red[w][lane][nt * 4] = (float4){pv[nt][0], pv[nt][1], pv[nt][2], pv[nt][3]};
  __syncthreads();

  if (t < 64){
    #pragma unroll
    for (int nt = 0; nt < 5; ++nt){
      float4 a = *(const float4*)&red[0][t][nt * 4];
      float4 b = *(const float4*)&red[1][t][nt * 4];
      float4 c = *(const float4*)&red[2][t][nt * 4];
      float4 d = *(const float4*)&red[3][t][nt * 4];
      pv[nt][0] = a.x + b.x + c.x + d.x;
      pv[nt][1] = a.y + b.y + c.y + d.y;
      pv[nt][2] = a.z + b.z + c.z + d.z;
      pv[nt][3] = a.w + b.w + c.w + d.w;
    }
    #pragma unroll
    for (int r = 0; r < 4; ++r){
      float den = __shfl(pv[4][r], quad * 16, 64);
      den = fmaxf(den, EPSF);
      float inv_den = 1.f / den;
      float g[4];
      float gsq = 0.f;
      #pragma unroll
      for (int nt = 0; nt < 4; ++nt){ g[nt] = pv[nt][r] * inv_den; gsq += g[nt] * g[nt]; }
      #pragma unroll
      for (int m = 8; m >= 1; m >>= 1) gsq += __shfl_xor(gsq, m, 64);
      float gn = fmaxf(sqrtf(gsq), EPSF);
      float x = fminf(gn, 1.f - 1e-7f);
      float tt2 = x / (1.f + sqrtf(1.f - x * x));
      float scl = (tt2 / gn) * beta_scale;
      const int q = q0 + quad * 4 + r;
      #pragma unroll
      for (int nt = 0; nt < 4; ++nt)
        out[(size_t)q * EDIM + h * HD + 16 * nt + col] = g[nt] * scl;
    }
  }
}

extern "C" void kernel_launch(void* const* d_in, const int* in_sizes, int n_in,
                              void* d_out, int out_size, void* d_ws, size_t ws_size,
                              hipStream_t stream){
  const void* Xq  = d_in[0];
  const void* Xk  = d_in[1];
  const void* Xv  = d_in[2];
  const void* Wq  = d_in[3];
  const void* Wk  = d_in[4];
  const void* Wv  = d_in[5];
  const void* Bq  = d_in[6];
  const void* Bk  = d_in[7];
  const void* Bv  = d_in[8];
  const void* tau = d_in[9];
  const void* gam = d_in[10];

  float* wsf   = (float*)d_ws;
  float* zn    = wsf + ZN_OFF;
  float* stats = wsf + STATS_OFF;
  float* cqs   = wsf + CQ_OFF;
  float* iks   = wsf + IK_OFF;
  unsigned short* u16b = (unsigned short*)(wsf + U16_OFF);
  unsigned short* WT   = u16b + WT_U16;
  unsigned short* qkvb = u16b + QKVB_U16;
  unsigned short* VT   = u16b + VT_U16;
  float* big   = wsf + BIG_OFF;

  const int use_part = (ws_size >= (size_t)(BIG_OFF + PART_FLOATS) * sizeof(float)) ? 1 : 0;

  unsigned short* Qb = qkvb;
  unsigned short* Kb = qkvb + (size_t)H * SEQ * HD;
  float* q2s = stats;
  float* k2s = stats + (size_t)H * SEQ;
  const unsigned short* qprobe = (const unsigned short*)Xq;

  double lb1 = lgamma(EDIM / 2.0) + lgamma(0.5) - lgamma(EDIM / 2.0 + 0.5);
  double lb2 = lgamma(HD / 2.0)   + lgamma(0.5) - lgamma(HD / 2.0 + 0.5);
  float beta_scale = (float)exp(lb1 - lb2);

  hipMemsetAsync(zn, 0, (size_t)(3 * EDIM) * sizeof(float), stream);
  if (!use_part)
    hipMemsetAsync(big, 0, (size_t)ACC_FLOATS * sizeof(float), stream);
  wcvt_kernel<<<dim3(64, 3), dim3(256), 0, stream>>>(Wq, Wk, Wv, qprobe, WT, zn);
  hlinear_kernel<<<dim3(SEQ / 16, 3), dim3(256), 0, stream>>>(
      Xq, Xk, Xv, WT, Bq, Bk, Bv, zn, qkvb, stats, cqs, iks, VT);
  attn_kernel<<<dim3(32 * 8, H), dim3(256), 0, stream>>>(
      Qb, Kb, VT, q2s, k2s, cqs, iks, tau, gam, qprobe, big, use_part);
  attn_fin_kernel<<<dim3(128, H), dim3(256), 0, stream>>>(
      big, use_part, (float*)d_out, beta_scale);
}

// Round 19
// 211.757 us; speedup vs baseline: 1.0167x; 1.0143x over previous
//
#include <hip/hip_runtime.h>
#include <cmath>

#define H 8
#define SEQ 2048
#define EDIM 512
#define HD 64
#define EPSF 1e-15f

typedef short bf16x8 __attribute__((ext_vector_type(8)));
typedef float f32x4 __attribute__((ext_vector_type(4)));

// workspace layout (float offsets; 16B-aligned)
#define ZN_OFF    16                                // 3*EDIM
#define STATS_OFF (ZN_OFF + 3 * EDIM)               // 3*H*SEQ fp32 (rounded q2/k2/v2)
#define CQ_OFF    (STATS_OFF + 3 * H * SEQ)         // H*SEQ: 2/(1-q2)
#define IK_OFF    (CQ_OFF + H * SEQ)                // H*SEQ: 1/(1-k2)
#define U16_OFF   (IK_OFF + H * SEQ + 16)
#define WT_U16    0
#define QKVB_U16  (WT_U16 + 3 * EDIM * EDIM)
#define VT_U16    (QKVB_U16 + 3 * SEQ * EDIM)
#define U16_TOTAL (VT_U16 + H * 80 * SEQ)
#define BIG_OFF   (U16_OFF + U16_TOTAL / 2 + 16)    // part (42MB) or ACC (5.2MB) region
#define PART_FLOATS (8 * 32 * 8 * 4 * 320 * 4)      // 10,485,760 floats
#define ACC_FLOATS  (H * SEQ * 80)

__device__ __forceinline__ float bf2f(unsigned short u){
  union { unsigned int i; float f; } v; v.i = ((unsigned int)u) << 16; return v.f;
}
__device__ __forceinline__ unsigned short f2bf(float f){
  union { float f; unsigned int i; } v; v.f = f;
  unsigned int x = v.i;
  unsigned int r = (x + 0x7fffu + ((x >> 16) & 1u)) >> 16;
  return (unsigned short)r;
}

// inline dtype detect: bf16-interpret first 256 u16 of query; fp32 data decodes
// to huge magnitudes w.p. ~1. Butterfly max -> wave-uniform result, no dispatch.
__device__ __forceinline__ int detect_f32(const unsigned short* __restrict__ q){
  const int l = threadIdx.x & 63;
  float mx = 0.f;
  #pragma unroll
  for (int j = 0; j < 4; ++j) mx = fmaxf(mx, fabsf(bf2f(q[l * 4 + j])));
  #pragma unroll
  for (int m = 32; m >= 1; m >>= 1) mx = fmaxf(mx, __shfl_xor(mx, m, 64));
  return mx > 1000.f;
}

// P1: W -> WT bf16 [p][o][i] (transpose) + fp32 column sumsq into zn (pre-zeroed).
__global__ __launch_bounds__(256) void wcvt_kernel(
    const void* __restrict__ Wq, const void* __restrict__ Wk, const void* __restrict__ Wv,
    const unsigned short* __restrict__ qprobe,
    unsigned short* __restrict__ WT, float* __restrict__ zn)
{
  const int p = blockIdx.y;
  const int bi = blockIdx.x >> 3, bo = blockIdx.x & 7;
  const void* W = (p == 0) ? Wq : ((p == 1) ? Wk : Wv);
  const int t = threadIdx.x;
  const int isf32 = detect_f32(qprobe);
  __shared__ float tile[64][65];

  #pragma unroll
  for (int j = 0; j < 16; ++j){
    int idx = t + 256 * j;
    int il = idx >> 6, ol = idx & 63;
    float val;
    if (isf32) val = ((const float*)W)[(size_t)(bi * 64 + il) * EDIM + bo * 64 + ol];
    else       val = bf2f(((const unsigned short*)W)[(size_t)(bi * 64 + il) * EDIM + bo * 64 + ol]);
    tile[il][ol] = val;
  }
  __syncthreads();
  if (t < 64){
    float s = 0.f;
    #pragma unroll 8
    for (int i = 0; i < 64; ++i){ float v = tile[i][t]; s += v * v; }
    atomicAdd(&zn[p * EDIM + bo * 64 + t], s);
  }
  #pragma unroll
  for (int j = 0; j < 16; ++j){
    int idx = t + 256 * j;
    int ol = idx >> 6, il = idx & 63;
    WT[((size_t)p * EDIM + bo * 64 + ol) * EDIM + bi * 64 + il] = f2bf(tile[il][ol]);
  }
}

// K1: hyperbolic linear via MFMA, 16 rows/block, X conversion fused, with an
// explicit register double-buffer on the ks loop (A + 8 B frags one iter ahead).
__global__ __launch_bounds__(256) void hlinear_kernel(
    const void* __restrict__ Xq, const void* __restrict__ Xk, const void* __restrict__ Xv,
    const unsigned short* __restrict__ WT,
    const void* __restrict__ Bq, const void* __restrict__ Bk, const void* __restrict__ Bv,
    const float* __restrict__ znacc,
    unsigned short* __restrict__ qkvb, float* __restrict__ stats,
    float* __restrict__ cqs, float* __restrict__ iks,
    unsigned short* __restrict__ VT)
{
  const int p = blockIdx.y;
  const void* X  = (p == 0) ? Xq : ((p == 1) ? Xk : Xv);
  const void* Bb = (p == 0) ? Bq : ((p == 1) ? Bk : Bv);
  const int r0 = blockIdx.x * 16;
  const int t  = threadIdx.x;
  const int w = t >> 6, lane = t & 63;
  const int col = lane & 15, quad = lane >> 4;
  const int isf32 = detect_f32((const unsigned short*)Xq);

  __shared__ float smem[16 * EDIM];
  __shared__ float sw2[16];

  const unsigned short* WTb = WT + ((size_t)p * EDIM + w * 128 + col) * EDIM;
  const float* Xf = (const float*)X + (size_t)(r0 + col) * EDIM;
  const unsigned short* Xh = (const unsigned short*)X + (size_t)(r0 + col) * EDIM;

  f32x4 acc[8];
  #pragma unroll
  for (int nt = 0; nt < 8; ++nt) acc[nt] = (f32x4){0.f, 0.f, 0.f, 0.f};
  float x2part = 0.f;

  bf16x8 caf, naf;
  bf16x8 cbf[8], nbf[8];
  {
    if (isf32){
      float4 xa = *(const float4*)&Xf[quad * 8];
      float4 xb = *(const float4*)&Xf[quad * 8 + 4];
      float xv[8] = {xa.x, xa.y, xa.z, xa.w, xb.x, xb.y, xb.z, xb.w};
      #pragma unroll
      for (int j = 0; j < 8; ++j){ caf[j] = (short)f2bf(xv[j]); x2part += xv[j] * xv[j]; }
    } else {
      caf = *(const bf16x8*)&Xh[quad * 8];
      #pragma unroll
      for (int j = 0; j < 8; ++j){ float xv = bf2f((unsigned short)caf[j]); x2part += xv * xv; }
    }
    #pragma unroll
    for (int nt = 0; nt < 8; ++nt)
      cbf[nt] = *(const bf16x8*)&WTb[(size_t)nt * 16 * EDIM + quad * 8];
  }

  for (int ks = 0; ks < 16; ++ks){
    if (ks + 1 < 16){
      const int off = (ks + 1) * 32 + quad * 8;
      if (isf32){
        float4 xa = *(const float4*)&Xf[off];
        float4 xb = *(const float4*)&Xf[off + 4];
        float xv[8] = {xa.x, xa.y, xa.z, xa.w, xb.x, xb.y, xb.z, xb.w};
        #pragma unroll
        for (int j = 0; j < 8; ++j){ naf[j] = (short)f2bf(xv[j]); x2part += xv[j] * xv[j]; }
      } else {
        naf = *(const bf16x8*)&Xh[off];
        #pragma unroll
        for (int j = 0; j < 8; ++j){ float xv = bf2f((unsigned short)naf[j]); x2part += xv * xv; }
      }
      #pragma unroll
      for (int nt = 0; nt < 8; ++nt)
        nbf[nt] = *(const bf16x8*)&WTb[(size_t)nt * 16 * EDIM + off];
    }
    #pragma unroll
    for (int nt = 0; nt < 8; ++nt)
      acc[nt] = __builtin_amdgcn_mfma_f32_16x16x32_bf16(caf, cbf[nt], acc[nt], 0, 0, 0);
    if (ks + 1 < 16){
      caf = naf;
      #pragma unroll
      for (int nt = 0; nt < 8; ++nt) cbf[nt] = nbf[nt];
    }
  }
  x2part += __shfl_xor(x2part, 16, 64);
  x2part += __shfl_xor(x2part, 32, 64);
  float lamr[4], lm1[4];
  #pragma unroll
  for (int r = 0; r < 4; ++r){
    float x2r = __shfl(x2part, quad * 4 + r, 64);
    lamr[r] = 2.f / (1.f - x2r);
    lm1[r] = lamr[r] - 1.f;
  }
  #pragma unroll
  for (int nt = 0; nt < 8; ++nt){
    const int n = w * 128 + nt * 16 + col;
    float znv = fmaxf(sqrtf(znacc[p * EDIM + n]), EPSF);
    float rb;
    if (isf32) rb = ((const float*)Bb)[n];
    else       rb = bf2f(((const unsigned short*)Bb)[n]);
    float e2r = __expf(2.f * rb);
    float ie2r = 1.f / e2r;
    float ch = 0.5f * (e2r + ie2r), sh = 0.5f * (e2r - ie2r);
    float izn = 1.f / znv;
    float tz = 2.f * znv;
    #pragma unroll
    for (int r = 0; r < 4; ++r){
      float a = (acc[nt][r] * lamr[r] * izn) * ch - lm1[r] * sh;
      float b = a + sqrtf(a * a + 1.f);
      float tt = __expf(tz * __logf(b));
      smem[(quad * 4 + r) * EDIM + n] = 0.5f * (tt - 1.f / tt);
    }
  }
  __syncthreads();

  {
    int row = t >> 4, l = t & 15;
    float s = 0.f;
    for (int o = l; o < EDIM; o += 16){ float wv = smem[row * EDIM + o]; s += wv * wv; }
    #pragma unroll
    for (int m = 8; m >= 1; m >>= 1) s += __shfl_xor(s, m, 16);
    if (l == 0) sw2[row] = s;
  }
  __syncthreads();

  const int o0 = 2 * t;
  const int h0 = t >> 5;
  const int d0 = o0 & 63;
  const int l5 = t & 31;
  #pragma unroll
  for (int rr = 0; rr < 16; ++rr){
    float inv = 1.f / (1.f + sqrtf(1.f + sw2[rr]));
    unsigned short b0 = f2bf(smem[rr * EDIM + o0] * inv);
    unsigned short b1 = f2bf(smem[rr * EDIM + o0 + 1] * inv);
    float r0v = bf2f(b0), r1v = bf2f(b1);
    int s = r0 + rr;
    unsigned int* dst = (unsigned int*)&qkvb[(((size_t)p * H + h0) * SEQ + s) * HD + d0];
    *dst = (unsigned int)b0 | ((unsigned int)b1 << 16);
    float ss = r0v * r0v + r1v * r1v;
    #pragma unroll
    for (int m = 16; m >= 1; m >>= 1) ss += __shfl_xor(ss, m, 64);
    if (p == 2){
      float lam = 2.f / (1.f - ss);
      VT[((size_t)h0 * 80 + d0) * SEQ + s]     = f2bf(r0v * lam);
      VT[((size_t)h0 * 80 + d0 + 1) * SEQ + s] = f2bf(r1v * lam);
      if (l5 < 16)
        VT[((size_t)h0 * 80 + 64 + l5) * SEQ + s] = (l5 == 0) ? f2bf(lam - 1.f) : 0;
    }
    if (l5 == 0){
      stats[((size_t)p * H + h0) * SEQ + s] = ss;
      if (p == 0) cqs[(size_t)h0 * SEQ + s] = 2.f / (1.f - ss);
      if (p == 1) iks[(size_t)h0 * SEQ + s] = 1.f / (1.f - ss);
    }
  }
}

// K3a: attention — frozen pipelined body; ONE change: LPT dispatch
// (tile = 31 - bx>>3 -> heavy 4-chunk blocks launch first, light blocks and
// immediate-exits backfill the drain tail). Collision-free part stores.
__global__ __launch_bounds__(256) void attn_kernel(
    const unsigned short* __restrict__ Qb, const unsigned short* __restrict__ Kb,
    const unsigned short* __restrict__ VT,
    const float* __restrict__ q2s_all, const float* __restrict__ k2s_all,
    const float* __restrict__ cqs_all, const float* __restrict__ iks_all,
    const void* __restrict__ tau, const void* __restrict__ gam,
    const unsigned short* __restrict__ qprobe,
    float* __restrict__ big, int use_part)
{
  const int h  = blockIdx.y;
  const int tile = 31 - (blockIdx.x >> 3);   // LPT: heaviest supertiles first
  const int sl = blockIdx.x & 7;
  if (sl > tile) return;
  const int t = threadIdx.x;
  const int w = t >> 6, lane = t & 63;
  const int col = lane & 15, quad = lane >> 4;
  const int q0 = tile * 64 + w * 16;

  const unsigned short* Qh  = Qb + (size_t)h * SEQ * HD;
  const unsigned short* Kh  = Kb + (size_t)h * SEQ * HD;
  const unsigned short* VTh = VT + (size_t)h * 80 * SEQ;
  const float* q2s = q2s_all + (size_t)h * SEQ;
  const float* k2s = k2s_all + (size_t)h * SEQ;
  const float* cqs = cqs_all + (size_t)h * SEQ;
  const float* iks = iks_all + (size_t)h * SEQ;

  const int isf32 = detect_f32(qprobe);
  float tauv, gamv;
  if (isf32){ tauv = ((const float*)tau)[0]; gamv = ((const float*)gam)[0]; }
  else      { tauv = bf2f(((const unsigned short*)tau)[0]);
              gamv = bf2f(((const unsigned short*)gam)[0]); }
  const float e_tau = __expf(tauv);

  const int srcA = ((quad & 1) * 2) * 16 + col;
  const int srcB = srcA + 16;
  const int tsel = quad >> 1;

  bf16x8 qf0 = *(const bf16x8*)&Qh[(size_t)(q0 + col) * HD + quad * 8];
  bf16x8 qf1 = *(const bf16x8*)&Qh[(size_t)(q0 + col) * HD + 32 + quad * 8];
  const float q2 = q2s[q0 + col];
  const float cq = cqs[q0 + col];
  const int qmax = q0 + col;

  f32x4 pv[5];
  #pragma unroll
  for (int nt = 0; nt < 5; ++nt) pv[nt] = (f32x4){0.f, 0.f, 0.f, 0.f};

  const int nch = ((tile - sl) >> 3) + 1;
  const int nhalf = nch * 2;
  int kb32 = sl * 64;

  bf16x8 ckf0[2], ckf1[2], nkf0[2], nkf1[2];
  float4 ck2[2], cik[2], nk2[2], nik[2];
  #pragma unroll
  for (int tt = 0; tt < 2; ++tt){
    const int kbase = kb32 + 16 * tt;
    ckf0[tt] = *(const bf16x8*)&Kh[(size_t)(kbase + col) * HD + quad * 8];
    ckf1[tt] = *(const bf16x8*)&Kh[(size_t)(kbase + col) * HD + 32 + quad * 8];
    ck2[tt]  = *(const float4*)&k2s[kbase + quad * 4];
    cik[tt]  = *(const float4*)&iks[kbase + quad * 4];
  }

  for (int i = 0; i < nhalf; ++i){
    const int nkb32 = (i & 1) ? (kb32 + 512 - 32) : (kb32 + 32);
    const bool have_next = (i + 1 < nhalf);
    if (have_next){
      #pragma unroll
      for (int tt = 0; tt < 2; ++tt){
        const int kbase = nkb32 + 16 * tt;
        nkf0[tt] = *(const bf16x8*)&Kh[(size_t)(kbase + col) * HD + quad * 8];
        nkf1[tt] = *(const bf16x8*)&Kh[(size_t)(kbase + col) * HD + 32 + quad * 8];
        nk2[tt]  = *(const float4*)&k2s[kbase + quad * 4];
        nik[tt]  = *(const float4*)&iks[kbase + quad * 4];
      }
    }

    unsigned int tlo[2], thi[2];
    #pragma unroll
    for (int tt = 0; tt < 2; ++tt){
      const int kbase = kb32 + 16 * tt;
      f32x4 s = (f32x4){0.f, 0.f, 0.f, 0.f};
      s = __builtin_amdgcn_mfma_f32_16x16x32_bf16(ckf0[tt], qf0, s, 0, 0, 0);
      s = __builtin_amdgcn_mfma_f32_16x16x32_bf16(ckf1[tt], qf1, s, 0, 0, 0);
      unsigned short pb[4];
      #pragma unroll
      for (int r = 0; r < 4; ++r){
        float k2 = (r == 0) ? ck2[tt].x : (r == 1) ? ck2[tt].y : (r == 2) ? ck2[tt].z : ck2[tt].w;
        float ik = (r == 0) ? cik[tt].x : (r == 1) ? cik[tt].y : (r == 2) ? cik[tt].z : cik[tt].w;
        float diff2 = fmaxf(q2 + k2 - 2.f * s[r], 0.f);
        float u = fmaxf(diff2 * cq * ik, 1e-7f);
        float z = 1.f + u + sqrtf(u * (u + 2.f));
        float dist = __logf(z);
        float wv = __expf(-e_tau * dist - gamv);
        int key = kbase + quad * 4 + r;
        if (key > qmax) wv = 0.f;
        pb[r] = f2bf(wv);
      }
      tlo[tt] = (unsigned int)pb[0] | ((unsigned int)pb[1] << 16);
      thi[tt] = (unsigned int)pb[2] | ((unsigned int)pb[3] << 16);
    }
    unsigned int a0 = (unsigned int)__shfl((int)tlo[0], srcA, 64);
    unsigned int a1 = (unsigned int)__shfl((int)tlo[1], srcA, 64);
    unsigned int b0 = (unsigned int)__shfl((int)thi[0], srcA, 64);
    unsigned int b1 = (unsigned int)__shfl((int)thi[1], srcA, 64);
    unsigned int c0 = (unsigned int)__shfl((int)tlo[0], srcB, 64);
    unsigned int c1 = (unsigned int)__shfl((int)tlo[1], srcB, 64);
    unsigned int d0 = (unsigned int)__shfl((int)thi[0], srcB, 64);
    unsigned int d1 = (unsigned int)__shfl((int)thi[1], srcB, 64);
    union { uint4 u; bf16x8 v; } pw;
    pw.u.x = tsel ? a1 : a0;
    pw.u.y = tsel ? b1 : b0;
    pw.u.z = tsel ? c1 : c0;
    pw.u.w = tsel ? d1 : d0;
    #pragma unroll
    for (int nt = 0; nt < 5; ++nt){
      bf16x8 vf = *(const bf16x8*)&VTh[(size_t)(16 * nt + col) * SEQ + kb32 + quad * 8];
      pv[nt] = __builtin_amdgcn_mfma_f32_16x16x32_bf16(pw.v, vf, pv[nt], 0, 0, 0);
    }

    if (have_next){
      #pragma unroll
      for (int tt = 0; tt < 2; ++tt){
        ckf0[tt] = nkf0[tt]; ckf1[tt] = nkf1[tt];
        ck2[tt] = nk2[tt];   cik[tt] = nik[tt];
      }
    }
    kb32 = nkb32;
  }

  if (use_part){
    float4* slot = (float4*)big +
        (size_t)(((((h * 32 + tile) * 8) + sl) * 4 + w)) * 320;
    #pragma unroll
    for (int nt = 0; nt < 5; ++nt)
      slot[nt * 64 + lane] = (float4){pv[nt][0], pv[nt][1], pv[nt][2], pv[nt][3]};
  } else {
    #pragma unroll
    for (int r = 0; r < 4; ++r){
      float* row = big + ((size_t)h * SEQ + q0 + quad * 4 + r) * 80;
      #pragma unroll
      for (int nt = 0; nt < 5; ++nt)
        atomicAdd(&row[16 * nt + col], pv[nt][r]);
    }
  }
}

// K3b: slice-sum (4 waves, <=2 serial reads each) + LDS reduce + gyromidpoint.
// Grid (128, H), 256 threads.
__global__ __launch_bounds__(256) void attn_fin_kernel(
    const float* __restrict__ big, int use_part,
    float* __restrict__ out, float beta_scale)
{
  const int h = blockIdx.y, tile16 = blockIdx.x;
  const int t = threadIdx.x;
  const int w = t >> 6, lane = t & 63;
  const int col = lane & 15, quad = lane >> 4;
  const int q0 = tile16 * 16;

  __shared__ float red[4][64][20];

  f32x4 pv[5];
  #pragma unroll
  for (int nt = 0; nt < 5; ++nt) pv[nt] = (f32x4){0.f, 0.f, 0.f, 0.f};

  if (use_part){
    const int st = tile16 >> 2, wq = tile16 & 3;
    const int nv = (st + 1 < 8) ? st + 1 : 8;
    for (int sl = w; sl < nv; sl += 4){
      const float4* slot = (const float4*)big +
          (size_t)(((((h * 32 + st) * 8) + sl) * 4 + wq)) * 320;
      #pragma unroll
      for (int nt = 0; nt < 5; ++nt){
        float4 v = slot[nt * 64 + lane];
        pv[nt][0] += v.x; pv[nt][1] += v.y; pv[nt][2] += v.z; pv[nt][3] += v.w;
      }
    }
  } else if (w == 0){
    #pragma unroll
    for (int nt = 0; nt < 5; ++nt)
      #pragma unroll
      for (int r = 0; r < 4; ++r)
        pv[nt][r] = big[((size_t)h * SEQ + q0 + quad * 4 + r) * 80 + 16 * nt + col];
  }

  #pragma unroll
  for (int nt = 0; nt < 5; ++nt)
    *(float4*)&red[w][lane][nt * 4] = (float4){pv[nt][0], pv[nt][1], pv[nt][2], pv[nt][3]};
  __syncthreads();

  if (t < 64){
    #pragma unroll
    for (int nt = 0; nt < 5; ++nt){
      float4 a = *(const float4*)&red[0][t][nt * 4];
      float4 b = *(const float4*)&red[1][t][nt * 4];
      float4 c = *(const float4*)&red[2][t][nt * 4];
      float4 d = *(const float4*)&red[3][t][nt * 4];
      pv[nt][0] = a.x + b.x + c.x + d.x;
      pv[nt][1] = a.y + b.y + c.y + d.y;
      pv[nt][2] = a.z + b.z + c.z + d.z;
      pv[nt][3] = a.w + b.w + c.w + d.w;
    }
    #pragma unroll
    for (int r = 0; r < 4; ++r){
      float den = __shfl(pv[4][r], quad * 16, 64);
      den = fmaxf(den, EPSF);
      float inv_den = 1.f / den;
      float g[4];
      float gsq = 0.f;
      #pragma unroll
      for (int nt = 0; nt < 4; ++nt){ g[nt] = pv[nt][r] * inv_den; gsq += g[nt] * g[nt]; }
      #pragma unroll
      for (int m = 8; m >= 1; m >>= 1) gsq += __shfl_xor(gsq, m, 64);
      float gn = fmaxf(sqrtf(gsq), EPSF);
      float x = fminf(gn, 1.f - 1e-7f);
      float tt2 = x / (1.f + sqrtf(1.f - x * x));
      float scl = (tt2 / gn) * beta_scale;
      const int q = q0 + quad * 4 + r;
      #pragma unroll
      for (int nt = 0; nt < 4; ++nt)
        out[(size_t)q * EDIM + h * HD + 16 * nt + col] = g[nt] * scl;
    }
  }
}

extern "C" void kernel_launch(void* const* d_in, const int* in_sizes, int n_in,
                              void* d_out, int out_size, void* d_ws, size_t ws_size,
                              hipStream_t stream){
  const void* Xq  = d_in[0];
  const void* Xk  = d_in[1];
  const void* Xv  = d_in[2];
  const void* Wq  = d_in[3];
  const void* Wk  = d_in[4];
  const void* Wv  = d_in[5];
  const void* Bq  = d_in[6];
  const void* Bk  = d_in[7];
  const void* Bv  = d_in[8];
  const void* tau = d_in[9];
  const void* gam = d_in[10];

  float* wsf   = (float*)d_ws;
  float* zn    = wsf + ZN_OFF;
  float* stats = wsf + STATS_OFF;
  float* cqs   = wsf + CQ_OFF;
  float* iks   = wsf + IK_OFF;
  unsigned short* u16b = (unsigned short*)(wsf + U16_OFF);
  unsigned short* WT   = u16b + WT_U16;
  unsigned short* qkvb = u16b + QKVB_U16;
  unsigned short* VT   = u16b + VT_U16;
  float* big   = wsf + BIG_OFF;

  const int use_part = (ws_size >= (size_t)(BIG_OFF + PART_FLOATS) * sizeof(float)) ? 1 : 0;

  unsigned short* Qb = qkvb;
  unsigned short* Kb = qkvb + (size_t)H * SEQ * HD;
  float* q2s = stats;
  float* k2s = stats + (size_t)H * SEQ;
  const unsigned short* qprobe = (const unsigned short*)Xq;

  double lb1 = lgamma(EDIM / 2.0) + lgamma(0.5) - lgamma(EDIM / 2.0 + 0.5);
  double lb2 = lgamma(HD / 2.0)   + lgamma(0.5) - lgamma(HD / 2.0 + 0.5);
  float beta_scale = (float)exp(lb1 - lb2);

  hipMemsetAsync(zn, 0, (size_t)(3 * EDIM) * sizeof(float), stream);
  if (!use_part)
    hipMemsetAsync(big, 0, (size_t)ACC_FLOATS * sizeof(float), stream);
  wcvt_kernel<<<dim3(64, 3), dim3(256), 0, stream>>>(Wq, Wk, Wv, qprobe, WT, zn);
  hlinear_kernel<<<dim3(SEQ / 16, 3), dim3(256), 0, stream>>>(
      Xq, Xk, Xv, WT, Bq, Bk, Bv, zn, qkvb, stats, cqs, iks, VT);
  attn_kernel<<<dim3(32 * 8, H), dim3(256), 0, stream>>>(
      Qb, Kb, VT, q2s, k2s, cqs, iks, tau, gam, qprobe, big, use_part);
  attn_fin_kernel<<<dim3(128, H), dim3(256), 0, stream>>>(
      big, use_part, (float*)d_out, beta_scale);
}

// Round 20
// 211.705 us; speedup vs baseline: 1.0169x; 1.0002x over previous
//
#include <hip/hip_runtime.h>
#include <cmath>

#define H 8
#define SEQ 2048
#define EDIM 512
#define HD 64
#define EPSF 1e-15f

typedef short bf16x8 __attribute__((ext_vector_type(8)));
typedef float f32x4 __attribute__((ext_vector_type(4)));

// workspace layout (float offsets; 16B-aligned)
#define ZN_OFF    16                                // 8 bi-slots x 3 x EDIM partial sums
#define STATS_OFF (ZN_OFF + 24 * EDIM)              // 3*H*SEQ fp32 (rounded q2/k2/v2)
#define CQ_OFF    (STATS_OFF + 3 * H * SEQ)         // H*SEQ: 2/(1-q2)
#define IK_OFF    (CQ_OFF + H * SEQ)                // H*SEQ: 1/(1-k2)
#define U16_OFF   (IK_OFF + H * SEQ + 16)
#define WT_U16    0
#define QKVB_U16  (WT_U16 + 3 * EDIM * EDIM)
#define VT_U16    (QKVB_U16 + 3 * SEQ * EDIM)
#define U16_TOTAL (VT_U16 + H * 80 * SEQ)
#define BIG_OFF   (U16_OFF + U16_TOTAL / 2 + 16)    // bf16 part (21MB) or fp32 ACC (5.2MB)
#define PART_U16S (8 * 32 * 8 * 4 * 1280)           // 10,485,760 u16 = 21 MB
#define ACC_FLOATS  (H * SEQ * 80)

__device__ __forceinline__ float bf2f(unsigned short u){
  union { unsigned int i; float f; } v; v.i = ((unsigned int)u) << 16; return v.f;
}
__device__ __forceinline__ unsigned short f2bf(float f){
  union { float f; unsigned int i; } v; v.f = f;
  unsigned int x = v.i;
  unsigned int r = (x + 0x7fffu + ((x >> 16) & 1u)) >> 16;
  return (unsigned short)r;
}

// inline dtype detect: bf16-interpret first 256 u16 of query; fp32 data decodes
// to huge magnitudes w.p. ~1. Butterfly max -> wave-uniform result, no dispatch.
__device__ __forceinline__ int detect_f32(const unsigned short* __restrict__ q){
  const int l = threadIdx.x & 63;
  float mx = 0.f;
  #pragma unroll
  for (int j = 0; j < 4; ++j) mx = fmaxf(mx, fabsf(bf2f(q[l * 4 + j])));
  #pragma unroll
  for (int m = 32; m >= 1; m >>= 1) mx = fmaxf(mx, __shfl_xor(mx, m, 64));
  return mx > 1000.f;
}

// P1: W -> WT bf16 [p][o][i] (transpose) + per-bi partial column sumsq (no atomics,
// no pre-zero): zn_part[bi][p][col].
__global__ __launch_bounds__(256) void wcvt_kernel(
    const void* __restrict__ Wq, const void* __restrict__ Wk, const void* __restrict__ Wv,
    const unsigned short* __restrict__ qprobe,
    unsigned short* __restrict__ WT, float* __restrict__ zn)
{
  const int p = blockIdx.y;
  const int bi = blockIdx.x >> 3, bo = blockIdx.x & 7;
  const void* W = (p == 0) ? Wq : ((p == 1) ? Wk : Wv);
  const int t = threadIdx.x;
  const int isf32 = detect_f32(qprobe);
  __shared__ float tile[64][65];

  #pragma unroll
  for (int j = 0; j < 16; ++j){
    int idx = t + 256 * j;
    int il = idx >> 6, ol = idx & 63;
    float val;
    if (isf32) val = ((const float*)W)[(size_t)(bi * 64 + il) * EDIM + bo * 64 + ol];
    else       val = bf2f(((const unsigned short*)W)[(size_t)(bi * 64 + il) * EDIM + bo * 64 + ol]);
    tile[il][ol] = val;
  }
  __syncthreads();
  if (t < 64){
    float s = 0.f;
    #pragma unroll 8
    for (int i = 0; i < 64; ++i){ float v = tile[i][t]; s += v * v; }
    zn[((size_t)(bi * 3 + p)) * EDIM + bo * 64 + t] = s;
  }
  #pragma unroll
  for (int j = 0; j < 16; ++j){
    int idx = t + 256 * j;
    int ol = idx >> 6, il = idx & 63;
    WT[((size_t)p * EDIM + bo * 64 + ol) * EDIM + bi * 64 + il] = f2bf(tile[il][ol]);
  }
}

// K1: hyperbolic linear via MFMA, 16 rows/block, X conversion fused, register
// double-buffer on the ks loop. znv = sqrt(sum of 8 zn_part slots).
__global__ __launch_bounds__(256) void hlinear_kernel(
    const void* __restrict__ Xq, const void* __restrict__ Xk, const void* __restrict__ Xv,
    const unsigned short* __restrict__ WT,
    const void* __restrict__ Bq, const void* __restrict__ Bk, const void* __restrict__ Bv,
    const float* __restrict__ znacc,
    unsigned short* __restrict__ qkvb, float* __restrict__ stats,
    float* __restrict__ cqs, float* __restrict__ iks,
    unsigned short* __restrict__ VT)
{
  const int p = blockIdx.y;
  const void* X  = (p == 0) ? Xq : ((p == 1) ? Xk : Xv);
  const void* Bb = (p == 0) ? Bq : ((p == 1) ? Bk : Bv);
  const int r0 = blockIdx.x * 16;
  const int t  = threadIdx.x;
  const int w = t >> 6, lane = t & 63;
  const int col = lane & 15, quad = lane >> 4;
  const int isf32 = detect_f32((const unsigned short*)Xq);

  __shared__ float smem[16 * EDIM];
  __shared__ float sw2[16];

  const unsigned short* WTb = WT + ((size_t)p * EDIM + w * 128 + col) * EDIM;
  const float* Xf = (const float*)X + (size_t)(r0 + col) * EDIM;
  const unsigned short* Xh = (const unsigned short*)X + (size_t)(r0 + col) * EDIM;

  f32x4 acc[8];
  #pragma unroll
  for (int nt = 0; nt < 8; ++nt) acc[nt] = (f32x4){0.f, 0.f, 0.f, 0.f};
  float x2part = 0.f;

  bf16x8 caf, naf;
  bf16x8 cbf[8], nbf[8];
  {
    if (isf32){
      float4 xa = *(const float4*)&Xf[quad * 8];
      float4 xb = *(const float4*)&Xf[quad * 8 + 4];
      float xv[8] = {xa.x, xa.y, xa.z, xa.w, xb.x, xb.y, xb.z, xb.w};
      #pragma unroll
      for (int j = 0; j < 8; ++j){ caf[j] = (short)f2bf(xv[j]); x2part += xv[j] * xv[j]; }
    } else {
      caf = *(const bf16x8*)&Xh[quad * 8];
      #pragma unroll
      for (int j = 0; j < 8; ++j){ float xv = bf2f((unsigned short)caf[j]); x2part += xv * xv; }
    }
    #pragma unroll
    for (int nt = 0; nt < 8; ++nt)
      cbf[nt] = *(const bf16x8*)&WTb[(size_t)nt * 16 * EDIM + quad * 8];
  }

  for (int ks = 0; ks < 16; ++ks){
    if (ks + 1 < 16){
      const int off = (ks + 1) * 32 + quad * 8;
      if (isf32){
        float4 xa = *(const float4*)&Xf[off];
        float4 xb = *(const float4*)&Xf[off + 4];
        float xv[8] = {xa.x, xa.y, xa.z, xa.w, xb.x, xb.y, xb.z, xb.w};
        #pragma unroll
        for (int j = 0; j < 8; ++j){ naf[j] = (short)f2bf(xv[j]); x2part += xv[j] * xv[j]; }
      } else {
        naf = *(const bf16x8*)&Xh[off];
        #pragma unroll
        for (int j = 0; j < 8; ++j){ float xv = bf2f((unsigned short)naf[j]); x2part += xv * xv; }
      }
      #pragma unroll
      for (int nt = 0; nt < 8; ++nt)
        nbf[nt] = *(const bf16x8*)&WTb[(size_t)nt * 16 * EDIM + off];
    }
    #pragma unroll
    for (int nt = 0; nt < 8; ++nt)
      acc[nt] = __builtin_amdgcn_mfma_f32_16x16x32_bf16(caf, cbf[nt], acc[nt], 0, 0, 0);
    if (ks + 1 < 16){
      caf = naf;
      #pragma unroll
      for (int nt = 0; nt < 8; ++nt) cbf[nt] = nbf[nt];
    }
  }
  x2part += __shfl_xor(x2part, 16, 64);
  x2part += __shfl_xor(x2part, 32, 64);
  float lamr[4], lm1[4];
  #pragma unroll
  for (int r = 0; r < 4; ++r){
    float x2r = __shfl(x2part, quad * 4 + r, 64);
    lamr[r] = 2.f / (1.f - x2r);
    lm1[r] = lamr[r] - 1.f;
  }
  #pragma unroll
  for (int nt = 0; nt < 8; ++nt){
    const int n = w * 128 + nt * 16 + col;
    float zsum = 0.f;
    #pragma unroll
    for (int bi = 0; bi < 8; ++bi)
      zsum += znacc[((size_t)(bi * 3 + p)) * EDIM + n];
    float znv = fmaxf(sqrtf(zsum), EPSF);
    float rb;
    if (isf32) rb = ((const float*)Bb)[n];
    else       rb = bf2f(((const unsigned short*)Bb)[n]);
    float e2r = __expf(2.f * rb);
    float ie2r = 1.f / e2r;
    float ch = 0.5f * (e2r + ie2r), sh = 0.5f * (e2r - ie2r);
    float izn = 1.f / znv;
    float tz = 2.f * znv;
    #pragma unroll
    for (int r = 0; r < 4; ++r){
      float a = (acc[nt][r] * lamr[r] * izn) * ch - lm1[r] * sh;
      float b = a + sqrtf(a * a + 1.f);
      float tt = __expf(tz * __logf(b));
      smem[(quad * 4 + r) * EDIM + n] = 0.5f * (tt - 1.f / tt);
    }
  }
  __syncthreads();

  {
    int row = t >> 4, l = t & 15;
    float s = 0.f;
    for (int o = l; o < EDIM; o += 16){ float wv = smem[row * EDIM + o]; s += wv * wv; }
    #pragma unroll
    for (int m = 8; m >= 1; m >>= 1) s += __shfl_xor(s, m, 16);
    if (l == 0) sw2[row] = s;
  }
  __syncthreads();

  const int o0 = 2 * t;
  const int h0 = t >> 5;
  const int d0 = o0 & 63;
  const int l5 = t & 31;
  #pragma unroll
  for (int rr = 0; rr < 16; ++rr){
    float inv = 1.f / (1.f + sqrtf(1.f + sw2[rr]));
    unsigned short b0 = f2bf(smem[rr * EDIM + o0] * inv);
    unsigned short b1 = f2bf(smem[rr * EDIM + o0 + 1] * inv);
    float r0v = bf2f(b0), r1v = bf2f(b1);
    int s = r0 + rr;
    unsigned int* dst = (unsigned int*)&qkvb[(((size_t)p * H + h0) * SEQ + s) * HD + d0];
    *dst = (unsigned int)b0 | ((unsigned int)b1 << 16);
    float ss = r0v * r0v + r1v * r1v;
    #pragma unroll
    for (int m = 16; m >= 1; m >>= 1) ss += __shfl_xor(ss, m, 64);
    if (p == 2){
      float lam = 2.f / (1.f - ss);
      VT[((size_t)h0 * 80 + d0) * SEQ + s]     = f2bf(r0v * lam);
      VT[((size_t)h0 * 80 + d0 + 1) * SEQ + s] = f2bf(r1v * lam);
      if (l5 < 16)
        VT[((size_t)h0 * 80 + 64 + l5) * SEQ + s] = (l5 == 0) ? f2bf(lam - 1.f) : 0;
    }
    if (l5 == 0){
      stats[((size_t)p * H + h0) * SEQ + s] = ss;
      if (p == 0) cqs[(size_t)h0 * SEQ + s] = 2.f / (1.f - ss);
      if (p == 1) iks[(size_t)h0 * SEQ + s] = 1.f / (1.f - ss);
    }
  }
}

// K3a: attention — frozen R19 pipelined body + LPT dispatch; partials now
// stored as bf16 (halves WRITE traffic; no RMW, no collisions).
__global__ __launch_bounds__(256) void attn_kernel(
    const unsigned short* __restrict__ Qb, const unsigned short* __restrict__ Kb,
    const unsigned short* __restrict__ VT,
    const float* __restrict__ q2s_all, const float* __restrict__ k2s_all,
    const float* __restrict__ cqs_all, const float* __restrict__ iks_all,
    const void* __restrict__ tau, const void* __restrict__ gam,
    const unsigned short* __restrict__ qprobe,
    float* __restrict__ big, int use_part)
{
  const int h  = blockIdx.y;
  const int tile = 31 - (blockIdx.x >> 3);   // LPT: heaviest supertiles first
  const int sl = blockIdx.x & 7;
  if (sl > tile) return;
  const int t = threadIdx.x;
  const int w = t >> 6, lane = t & 63;
  const int col = lane & 15, quad = lane >> 4;
  const int q0 = tile * 64 + w * 16;

  const unsigned short* Qh  = Qb + (size_t)h * SEQ * HD;
  const unsigned short* Kh  = Kb + (size_t)h * SEQ * HD;
  const unsigned short* VTh = VT + (size_t)h * 80 * SEQ;
  const float* q2s = q2s_all + (size_t)h * SEQ;
  const float* k2s = k2s_all + (size_t)h * SEQ;
  const float* cqs = cqs_all + (size_t)h * SEQ;
  const float* iks = iks_all + (size_t)h * SEQ;

  const int isf32 = detect_f32(qprobe);
  float tauv, gamv;
  if (isf32){ tauv = ((const float*)tau)[0]; gamv = ((const float*)gam)[0]; }
  else      { tauv = bf2f(((const unsigned short*)tau)[0]);
              gamv = bf2f(((const unsigned short*)gam)[0]); }
  const float e_tau = __expf(tauv);

  const int srcA = ((quad & 1) * 2) * 16 + col;
  const int srcB = srcA + 16;
  const int tsel = quad >> 1;

  bf16x8 qf0 = *(const bf16x8*)&Qh[(size_t)(q0 + col) * HD + quad * 8];
  bf16x8 qf1 = *(const bf16x8*)&Qh[(size_t)(q0 + col) * HD + 32 + quad * 8];
  const float q2 = q2s[q0 + col];
  const float cq = cqs[q0 + col];
  const int qmax = q0 + col;

  f32x4 pv[5];
  #pragma unroll
  for (int nt = 0; nt < 5; ++nt) pv[nt] = (f32x4){0.f, 0.f, 0.f, 0.f};

  const int nch = ((tile - sl) >> 3) + 1;
  const int nhalf = nch * 2;
  int kb32 = sl * 64;

  bf16x8 ckf0[2], ckf1[2], nkf0[2], nkf1[2];
  float4 ck2[2], cik[2], nk2[2], nik[2];
  #pragma unroll
  for (int tt = 0; tt < 2; ++tt){
    const int kbase = kb32 + 16 * tt;
    ckf0[tt] = *(const bf16x8*)&Kh[(size_t)(kbase + col) * HD + quad * 8];
    ckf1[tt] = *(const bf16x8*)&Kh[(size_t)(kbase + col) * HD + 32 + quad * 8];
    ck2[tt]  = *(const float4*)&k2s[kbase + quad * 4];
    cik[tt]  = *(const float4*)&iks[kbase + quad * 4];
  }

  for (int i = 0; i < nhalf; ++i){
    const int nkb32 = (i & 1) ? (kb32 + 512 - 32) : (kb32 + 32);
    const bool have_next = (i + 1 < nhalf);
    if (have_next){
      #pragma unroll
      for (int tt = 0; tt < 2; ++tt){
        const int kbase = nkb32 + 16 * tt;
        nkf0[tt] = *(const bf16x8*)&Kh[(size_t)(kbase + col) * HD + quad * 8];
        nkf1[tt] = *(const bf16x8*)&Kh[(size_t)(kbase + col) * HD + 32 + quad * 8];
        nk2[tt]  = *(const float4*)&k2s[kbase + quad * 4];
        nik[tt]  = *(const float4*)&iks[kbase + quad * 4];
      }
    }

    unsigned int tlo[2], thi[2];
    #pragma unroll
    for (int tt = 0; tt < 2; ++tt){
      const int kbase = kb32 + 16 * tt;
      f32x4 s = (f32x4){0.f, 0.f, 0.f, 0.f};
      s = __builtin_amdgcn_mfma_f32_16x16x32_bf16(ckf0[tt], qf0, s, 0, 0, 0);
      s = __builtin_amdgcn_mfma_f32_16x16x32_bf16(ckf1[tt], qf1, s, 0, 0, 0);
      unsigned short pb[4];
      #pragma unroll
      for (int r = 0; r < 4; ++r){
        float k2 = (r == 0) ? ck2[tt].x : (r == 1) ? ck2[tt].y : (r == 2) ? ck2[tt].z : ck2[tt].w;
        float ik = (r == 0) ? cik[tt].x : (r == 1) ? cik[tt].y : (r == 2) ? cik[tt].z : cik[tt].w;
        float diff2 = fmaxf(q2 + k2 - 2.f * s[r], 0.f);
        float u = fmaxf(diff2 * cq * ik, 1e-7f);
        float z = 1.f + u + sqrtf(u * (u + 2.f));
        float dist = __logf(z);
        float wv = __expf(-e_tau * dist - gamv);
        int key = kbase + quad * 4 + r;
        if (key > qmax) wv = 0.f;
        pb[r] = f2bf(wv);
      }
      tlo[tt] = (unsigned int)pb[0] | ((unsigned int)pb[1] << 16);
      thi[tt] = (unsigned int)pb[2] | ((unsigned int)pb[3] << 16);
    }
    unsigned int a0 = (unsigned int)__shfl((int)tlo[0], srcA, 64);
    unsigned int a1 = (unsigned int)__shfl((int)tlo[1], srcA, 64);
    unsigned int b0 = (unsigned int)__shfl((int)thi[0], srcA, 64);
    unsigned int b1 = (unsigned int)__shfl((int)thi[1], srcA, 64);
    unsigned int c0 = (unsigned int)__shfl((int)tlo[0], srcB, 64);
    unsigned int c1 = (unsigned int)__shfl((int)tlo[1], srcB, 64);
    unsigned int d0 = (unsigned int)__shfl((int)thi[0], srcB, 64);
    unsigned int d1 = (unsigned int)__shfl((int)thi[1], srcB, 64);
    union { uint4 u; bf16x8 v; } pw;
    pw.u.x = tsel ? a1 : a0;
    pw.u.y = tsel ? b1 : b0;
    pw.u.z = tsel ? c1 : c0;
    pw.u.w = tsel ? d1 : d0;
    #pragma unroll
    for (int nt = 0; nt < 5; ++nt){
      bf16x8 vf = *(const bf16x8*)&VTh[(size_t)(16 * nt + col) * SEQ + kb32 + quad * 8];
      pv[nt] = __builtin_amdgcn_mfma_f32_16x16x32_bf16(pw.v, vf, pv[nt], 0, 0, 0);
    }

    if (have_next){
      #pragma unroll
      for (int tt = 0; tt < 2; ++tt){
        ckf0[tt] = nkf0[tt]; ckf1[tt] = nkf1[tt];
        ck2[tt] = nk2[tt];   cik[tt] = nik[tt];
      }
    }
    kb32 = nkb32;
  }

  if (use_part){
    uint2* slot = (uint2*)big + (size_t)((((h * 32 + tile) * 8) + sl) * 4 + w) * 320;
    #pragma unroll
    for (int nt = 0; nt < 5; ++nt){
      uint2 pk;
      pk.x = (unsigned int)f2bf(pv[nt][0]) | ((unsigned int)f2bf(pv[nt][1]) << 16);
      pk.y = (unsigned int)f2bf(pv[nt][2]) | ((unsigned int)f2bf(pv[nt][3]) << 16);
      slot[nt * 64 + lane] = pk;
    }
  } else {
    #pragma unroll
    for (int r = 0; r < 4; ++r){
      float* row = big + ((size_t)h * SEQ + q0 + quad * 4 + r) * 80;
      #pragma unroll
      for (int nt = 0; nt < 5; ++nt)
        atomicAdd(&row[16 * nt + col], pv[nt][r]);
    }
  }
}

// K3b: bf16-slice-sum (4 waves, <=2 serial reads each) + LDS reduce + gyromidpoint.
// Grid (128, H), 256 threads.
__global__ __launch_bounds__(256) void attn_fin_kernel(
    const float* __restrict__ big, int use_part,
    float* __restrict__ out, float beta_scale)
{
  const int h = blockIdx.y, tile16 = blockIdx.x;
  const int t = threadIdx.x;
  const int w = t >> 6, lane = t & 63;
  const int col = lane & 15, quad = lane >> 4;
  const int q0 = tile16 * 16;

  __shared__ float red[4][64][20];

  f32x4 pv[5];
  #pragma unroll
  for (int nt = 0; nt < 5; ++nt) pv[nt] = (f32x4){0.f, 0.f, 0.f, 0.f};

  if (use_part){
    const int st = tile16 >> 2, wq = tile16 & 3;
    const int nv = (st + 1 < 8) ? st + 1 : 8;
    for (int sl = w; sl < nv; sl += 4){
      const uint2* slot = (const uint2*)big +
          (size_t)((((h * 32 + st) * 8) + sl) * 4 + wq) * 320;
      #pragma unroll
      for (int nt = 0; nt < 5; ++nt){
        uint2 v = slot[nt * 64 + lane];
        pv[nt][0] += bf2f((unsigned short)(v.x & 0xffffu));
        pv[nt][1] += bf2f((unsigned short)(v.x >> 16));
        pv[nt][2] += bf2f((unsigned short)(v.y & 0xffffu));
        pv[nt][3] += bf2f((unsigned short)(v.y >> 16));
      }
    }
  } else if (w == 0){
    #pragma unroll
    for (int nt = 0; nt < 5; ++nt)
      #pragma unroll
      for (int r = 0; r < 4; ++r)
        pv[nt][r] = big[((size_t)h * SEQ + q0 + quad * 4 + r) * 80 + 16 * nt + col];
  }

  #pragma unroll
  for (int nt = 0; nt < 5; ++nt)
    *(float4*)&red[w][lane][nt * 4] = (float4){pv[nt][0], pv[nt][1], pv[nt][2], pv[nt][3]};
  __syncthreads();

  if (t < 64){
    #pragma unroll
    for (int nt = 0; nt < 5; ++nt){
      float4 a = *(const float4*)&red[0][t][nt * 4];
      float4 b = *(const float4*)&red[1][t][nt * 4];
      float4 c = *(const float4*)&red[2][t][nt * 4];
      float4 d = *(const float4*)&red[3][t][nt * 4];
      pv[nt][0] = a.x + b.x + c.x + d.x;
      pv[nt][1] = a.y + b.y + c.y + d.y;
      pv[nt][2] = a.z + b.z + c.z + d.z;
      pv[nt][3] = a.w + b.w + c.w + d.w;
    }
    #pragma unroll
    for (int r = 0; r < 4; ++r){
      float den = __shfl(pv[4][r], quad * 16, 64);
      den = fmaxf(den, EPSF);
      float inv_den = 1.f / den;
      float g[4];
      float gsq = 0.f;
      #pragma unroll
      for (int nt = 0; nt < 4; ++nt){ g[nt] = pv[nt][r] * inv_den; gsq += g[nt] * g[nt]; }
      #pragma unroll
      for (int m = 8; m >= 1; m >>= 1) gsq += __shfl_xor(gsq, m, 64);
      float gn = fmaxf(sqrtf(gsq), EPSF);
      float x = fminf(gn, 1.f - 1e-7f);
      float tt2 = x / (1.f + sqrtf(1.f - x * x));
      float scl = (tt2 / gn) * beta_scale;
      const int q = q0 + quad * 4 + r;
      #pragma unroll
      for (int nt = 0; nt < 4; ++nt)
        out[(size_t)q * EDIM + h * HD + 16 * nt + col] = g[nt] * scl;
    }
  }
}

extern "C" void kernel_launch(void* const* d_in, const int* in_sizes, int n_in,
                              void* d_out, int out_size, void* d_ws, size_t ws_size,
                              hipStream_t stream){
  const void* Xq  = d_in[0];
  const void* Xk  = d_in[1];
  const void* Xv  = d_in[2];
  const void* Wq  = d_in[3];
  const void* Wk  = d_in[4];
  const void* Wv  = d_in[5];
  const void* Bq  = d_in[6];
  const void* Bk  = d_in[7];
  const void* Bv  = d_in[8];
  const void* tau = d_in[9];
  const void* gam = d_in[10];

  float* wsf   = (float*)d_ws;
  float* zn    = wsf + ZN_OFF;
  float* stats = wsf + STATS_OFF;
  float* cqs   = wsf + CQ_OFF;
  float* iks   = wsf + IK_OFF;
  unsigned short* u16b = (unsigned short*)(wsf + U16_OFF);
  unsigned short* WT   = u16b + WT_U16;
  unsigned short* qkvb = u16b + QKVB_U16;
  unsigned short* VT   = u16b + VT_U16;
  float* big   = wsf + BIG_OFF;

  const int use_part =
      (ws_size >= (size_t)BIG_OFF * sizeof(float) + (size_t)PART_U16S * 2) ? 1 : 0;

  unsigned short* Qb = qkvb;
  unsigned short* Kb = qkvb + (size_t)H * SEQ * HD;
  float* q2s = stats;
  float* k2s = stats + (size_t)H * SEQ;
  const unsigned short* qprobe = (const unsigned short*)Xq;

  double lb1 = lgamma(EDIM / 2.0) + lgamma(0.5) - lgamma(EDIM / 2.0 + 0.5);
  double lb2 = lgamma(HD / 2.0)   + lgamma(0.5) - lgamma(HD / 2.0 + 0.5);
  float beta_scale = (float)exp(lb1 - lb2);

  if (!use_part)
    hipMemsetAsync(big, 0, (size_t)ACC_FLOATS * sizeof(float), stream);
  wcvt_kernel<<<dim3(64, 3), dim3(256), 0, stream>>>(Wq, Wk, Wv, qprobe, WT, zn);
  hlinear_kernel<<<dim3(SEQ / 16, 3), dim3(256), 0, stream>>>(
      Xq, Xk, Xv, WT, Bq, Bk, Bv, zn, qkvb, stats, cqs, iks, VT);
  attn_kernel<<<dim3(32 * 8, H), dim3(256), 0, stream>>>(
      Qb, Kb, VT, q2s, k2s, cqs, iks, tau, gam, qprobe, big, use_part);
  attn_fin_kernel<<<dim3(128, H), dim3(256), 0, stream>>>(
      big, use_part, (float*)d_out, beta_scale);
}

// Round 21
// 206.515 us; speedup vs baseline: 1.0425x; 1.0251x over previous
//
#include <hip/hip_runtime.h>
#include <cmath>

#define H 8
#define SEQ 2048
#define EDIM 512
#define HD 64
#define EPSF 1e-15f

typedef short bf16x8 __attribute__((ext_vector_type(8)));
typedef float f32x4 __attribute__((ext_vector_type(4)));

// workspace layout (float offsets; 16B-aligned)
#define ZN_OFF    16                                // 8 bi-slots x 3 x EDIM partial sums
#define STATS_OFF (ZN_OFF + 24 * EDIM)              // 3*H*SEQ fp32 (rounded q2/k2/v2)
#define CQ_OFF    (STATS_OFF + 3 * H * SEQ)         // H*SEQ: 2/(1-q2)
#define IK_OFF    (CQ_OFF + H * SEQ)                // H*SEQ: 1/(1-k2)
#define U16_OFF   (IK_OFF + H * SEQ + 16)
#define WT_U16    0
#define QKVB_U16  (WT_U16 + 3 * EDIM * EDIM)
#define VT_U16    (QKVB_U16 + 3 * SEQ * EDIM)
#define U16_TOTAL (VT_U16 + H * 80 * SEQ)
#define BIG_OFF   (U16_OFF + U16_TOTAL / 2 + 16)    // bf16 part (21MB) or fp32 ACC (5.2MB)
#define PART_U16S (8 * 32 * 8 * 4 * 1280)           // 10,485,760 u16 = 21 MB
#define ACC_FLOATS  (H * SEQ * 80)

__device__ __forceinline__ float bf2f(unsigned short u){
  union { unsigned int i; float f; } v; v.i = ((unsigned int)u) << 16; return v.f;
}
__device__ __forceinline__ unsigned short f2bf(float f){
  union { float f; unsigned int i; } v; v.f = f;
  unsigned int x = v.i;
  unsigned int r = (x + 0x7fffu + ((x >> 16) & 1u)) >> 16;
  return (unsigned short)r;
}

// inline dtype detect: bf16-interpret first 256 u16 of query; fp32 data decodes
// to huge magnitudes w.p. ~1. Butterfly max -> wave-uniform result, no dispatch.
__device__ __forceinline__ int detect_f32(const unsigned short* __restrict__ q){
  const int l = threadIdx.x & 63;
  float mx = 0.f;
  #pragma unroll
  for (int j = 0; j < 4; ++j) mx = fmaxf(mx, fabsf(bf2f(q[l * 4 + j])));
  #pragma unroll
  for (int m = 32; m >= 1; m >>= 1) mx = fmaxf(mx, __shfl_xor(mx, m, 64));
  return mx > 1000.f;
}

// P1: W -> WT bf16 [p][o][i] (transpose) + per-bi partial column sumsq (no atomics).
__global__ __launch_bounds__(256) void wcvt_kernel(
    const void* __restrict__ Wq, const void* __restrict__ Wk, const void* __restrict__ Wv,
    const unsigned short* __restrict__ qprobe,
    unsigned short* __restrict__ WT, float* __restrict__ zn)
{
  const int p = blockIdx.y;
  const int bi = blockIdx.x >> 3, bo = blockIdx.x & 7;
  const void* W = (p == 0) ? Wq : ((p == 1) ? Wk : Wv);
  const int t = threadIdx.x;
  const int isf32 = detect_f32(qprobe);
  __shared__ float tile[64][65];

  #pragma unroll
  for (int j = 0; j < 16; ++j){
    int idx = t + 256 * j;
    int il = idx >> 6, ol = idx & 63;
    float val;
    if (isf32) val = ((const float*)W)[(size_t)(bi * 64 + il) * EDIM + bo * 64 + ol];
    else       val = bf2f(((const unsigned short*)W)[(size_t)(bi * 64 + il) * EDIM + bo * 64 + ol]);
    tile[il][ol] = val;
  }
  __syncthreads();
  if (t < 64){
    float s = 0.f;
    #pragma unroll 8
    for (int i = 0; i < 64; ++i){ float v = tile[i][t]; s += v * v; }
    zn[((size_t)(bi * 3 + p)) * EDIM + bo * 64 + t] = s;
  }
  #pragma unroll
  for (int j = 0; j < 16; ++j){
    int idx = t + 256 * j;
    int ol = idx >> 6, il = idx & 63;
    WT[((size_t)p * EDIM + bo * 64 + ol) * EDIM + bi * 64 + il] = f2bf(tile[il][ol]);
  }
}

// K1: hyperbolic linear via MFMA, 16 rows/block, X conversion fused, register
// double-buffer on the ks loop. znv = sqrt(sum of 8 zn_part slots).
__global__ __launch_bounds__(256) void hlinear_kernel(
    const void* __restrict__ Xq, const void* __restrict__ Xk, const void* __restrict__ Xv,
    const unsigned short* __restrict__ WT,
    const void* __restrict__ Bq, const void* __restrict__ Bk, const void* __restrict__ Bv,
    const float* __restrict__ znacc,
    unsigned short* __restrict__ qkvb, float* __restrict__ stats,
    float* __restrict__ cqs, float* __restrict__ iks,
    unsigned short* __restrict__ VT)
{
  const int p = blockIdx.y;
  const void* X  = (p == 0) ? Xq : ((p == 1) ? Xk : Xv);
  const void* Bb = (p == 0) ? Bq : ((p == 1) ? Bk : Bv);
  const int r0 = blockIdx.x * 16;
  const int t  = threadIdx.x;
  const int w = t >> 6, lane = t & 63;
  const int col = lane & 15, quad = lane >> 4;
  const int isf32 = detect_f32((const unsigned short*)Xq);

  __shared__ float smem[16 * EDIM];
  __shared__ float sw2[16];

  const unsigned short* WTb = WT + ((size_t)p * EDIM + w * 128 + col) * EDIM;
  const float* Xf = (const float*)X + (size_t)(r0 + col) * EDIM;
  const unsigned short* Xh = (const unsigned short*)X + (size_t)(r0 + col) * EDIM;

  f32x4 acc[8];
  #pragma unroll
  for (int nt = 0; nt < 8; ++nt) acc[nt] = (f32x4){0.f, 0.f, 0.f, 0.f};
  float x2part = 0.f;

  bf16x8 caf, naf;
  bf16x8 cbf[8], nbf[8];
  {
    if (isf32){
      float4 xa = *(const float4*)&Xf[quad * 8];
      float4 xb = *(const float4*)&Xf[quad * 8 + 4];
      float xv[8] = {xa.x, xa.y, xa.z, xa.w, xb.x, xb.y, xb.z, xb.w};
      #pragma unroll
      for (int j = 0; j < 8; ++j){ caf[j] = (short)f2bf(xv[j]); x2part += xv[j] * xv[j]; }
    } else {
      caf = *(const bf16x8*)&Xh[quad * 8];
      #pragma unroll
      for (int j = 0; j < 8; ++j){ float xv = bf2f((unsigned short)caf[j]); x2part += xv * xv; }
    }
    #pragma unroll
    for (int nt = 0; nt < 8; ++nt)
      cbf[nt] = *(const bf16x8*)&WTb[(size_t)nt * 16 * EDIM + quad * 8];
  }

  for (int ks = 0; ks < 16; ++ks){
    if (ks + 1 < 16){
      const int off = (ks + 1) * 32 + quad * 8;
      if (isf32){
        float4 xa = *(const float4*)&Xf[off];
        float4 xb = *(const float4*)&Xf[off + 4];
        float xv[8] = {xa.x, xa.y, xa.z, xa.w, xb.x, xb.y, xb.z, xb.w};
        #pragma unroll
        for (int j = 0; j < 8; ++j){ naf[j] = (short)f2bf(xv[j]); x2part += xv[j] * xv[j]; }
      } else {
        naf = *(const bf16x8*)&Xh[off];
        #pragma unroll
        for (int j = 0; j < 8; ++j){ float xv = bf2f((unsigned short)naf[j]); x2part += xv * xv; }
      }
      #pragma unroll
      for (int nt = 0; nt < 8; ++nt)
        nbf[nt] = *(const bf16x8*)&WTb[(size_t)nt * 16 * EDIM + off];
    }
    #pragma unroll
    for (int nt = 0; nt < 8; ++nt)
      acc[nt] = __builtin_amdgcn_mfma_f32_16x16x32_bf16(caf, cbf[nt], acc[nt], 0, 0, 0);
    if (ks + 1 < 16){
      caf = naf;
      #pragma unroll
      for (int nt = 0; nt < 8; ++nt) cbf[nt] = nbf[nt];
    }
  }
  x2part += __shfl_xor(x2part, 16, 64);
  x2part += __shfl_xor(x2part, 32, 64);
  float lamr[4], lm1[4];
  #pragma unroll
  for (int r = 0; r < 4; ++r){
    float x2r = __shfl(x2part, quad * 4 + r, 64);
    lamr[r] = 2.f / (1.f - x2r);
    lm1[r] = lamr[r] - 1.f;
  }
  #pragma unroll
  for (int nt = 0; nt < 8; ++nt){
    const int n = w * 128 + nt * 16 + col;
    float zsum = 0.f;
    #pragma unroll
    for (int bi = 0; bi < 8; ++bi)
      zsum += znacc[((size_t)(bi * 3 + p)) * EDIM + n];
    float znv = fmaxf(sqrtf(zsum), EPSF);
    float rb;
    if (isf32) rb = ((const float*)Bb)[n];
    else       rb = bf2f(((const unsigned short*)Bb)[n]);
    float e2r = __expf(2.f * rb);
    float ie2r = 1.f / e2r;
    float ch = 0.5f * (e2r + ie2r), sh = 0.5f * (e2r - ie2r);
    float izn = 1.f / znv;
    float tz = 2.f * znv;
    #pragma unroll
    for (int r = 0; r < 4; ++r){
      float a = (acc[nt][r] * lamr[r] * izn) * ch - lm1[r] * sh;
      float b = a + sqrtf(a * a + 1.f);
      float tt = __expf(tz * __logf(b));
      smem[(quad * 4 + r) * EDIM + n] = 0.5f * (tt - 1.f / tt);
    }
  }
  __syncthreads();

  {
    int row = t >> 4, l = t & 15;
    float s = 0.f;
    for (int o = l; o < EDIM; o += 16){ float wv = smem[row * EDIM + o]; s += wv * wv; }
    #pragma unroll
    for (int m = 8; m >= 1; m >>= 1) s += __shfl_xor(s, m, 16);
    if (l == 0) sw2[row] = s;
  }
  __syncthreads();

  const int o0 = 2 * t;
  const int h0 = t >> 5;
  const int d0 = o0 & 63;
  const int l5 = t & 31;
  #pragma unroll
  for (int rr = 0; rr < 16; ++rr){
    float inv = 1.f / (1.f + sqrtf(1.f + sw2[rr]));
    unsigned short b0 = f2bf(smem[rr * EDIM + o0] * inv);
    unsigned short b1 = f2bf(smem[rr * EDIM + o0 + 1] * inv);
    float r0v = bf2f(b0), r1v = bf2f(b1);
    int s = r0 + rr;
    unsigned int* dst = (unsigned int*)&qkvb[(((size_t)p * H + h0) * SEQ + s) * HD + d0];
    *dst = (unsigned int)b0 | ((unsigned int)b1 << 16);
    float ss = r0v * r0v + r1v * r1v;
    #pragma unroll
    for (int m = 16; m >= 1; m >>= 1) ss += __shfl_xor(ss, m, 64);
    if (p == 2){
      float lam = 2.f / (1.f - ss);
      VT[((size_t)h0 * 80 + d0) * SEQ + s]     = f2bf(r0v * lam);
      VT[((size_t)h0 * 80 + d0 + 1) * SEQ + s] = f2bf(r1v * lam);
      if (l5 < 16)
        VT[((size_t)h0 * 80 + 64 + l5) * SEQ + s] = (l5 == 0) ? f2bf(lam - 1.f) : 0;
    }
    if (l5 == 0){
      stats[((size_t)p * H + h0) * SEQ + s] = ss;
      if (p == 0) cqs[(size_t)h0 * SEQ + s] = 2.f / (1.f - ss);
      if (p == 1) iks[(size_t)h0 * SEQ + s] = 1.f / (1.f - ss);
    }
  }
}

// K3a: attention — frozen pipelined body + LPT; now ONE WAVE PER BLOCK (the 4
// waves never shared anything; 64-thread blocks give the dispatcher wave-level
// packing/backfill instead of 4-SIMD-quantized allocation/retirement).
__global__ __launch_bounds__(64) void attn_kernel(
    const unsigned short* __restrict__ Qb, const unsigned short* __restrict__ Kb,
    const unsigned short* __restrict__ VT,
    const float* __restrict__ q2s_all, const float* __restrict__ k2s_all,
    const float* __restrict__ cqs_all, const float* __restrict__ iks_all,
    const void* __restrict__ tau, const void* __restrict__ gam,
    const unsigned short* __restrict__ qprobe,
    float* __restrict__ big, int use_part)
{
  const int h  = blockIdx.y;
  const int tile = 31 - (blockIdx.x >> 5);   // LPT: heaviest supertiles first
  const int sl = (blockIdx.x >> 2) & 7;      // k-slice
  const int w  = blockIdx.x & 3;             // q-subtile (was wave id)
  if (sl > tile) return;
  const int lane = threadIdx.x;
  const int col = lane & 15, quad = lane >> 4;
  const int q0 = tile * 64 + w * 16;

  const unsigned short* Qh  = Qb + (size_t)h * SEQ * HD;
  const unsigned short* Kh  = Kb + (size_t)h * SEQ * HD;
  const unsigned short* VTh = VT + (size_t)h * 80 * SEQ;
  const float* q2s = q2s_all + (size_t)h * SEQ;
  const float* k2s = k2s_all + (size_t)h * SEQ;
  const float* cqs = cqs_all + (size_t)h * SEQ;
  const float* iks = iks_all + (size_t)h * SEQ;

  const int isf32 = detect_f32(qprobe);
  float tauv, gamv;
  if (isf32){ tauv = ((const float*)tau)[0]; gamv = ((const float*)gam)[0]; }
  else      { tauv = bf2f(((const unsigned short*)tau)[0]);
              gamv = bf2f(((const unsigned short*)gam)[0]); }
  const float e_tau = __expf(tauv);

  const int srcA = ((quad & 1) * 2) * 16 + col;
  const int srcB = srcA + 16;
  const int tsel = quad >> 1;

  bf16x8 qf0 = *(const bf16x8*)&Qh[(size_t)(q0 + col) * HD + quad * 8];
  bf16x8 qf1 = *(const bf16x8*)&Qh[(size_t)(q0 + col) * HD + 32 + quad * 8];
  const float q2 = q2s[q0 + col];
  const float cq = cqs[q0 + col];
  const int qmax = q0 + col;

  f32x4 pv[5];
  #pragma unroll
  for (int nt = 0; nt < 5; ++nt) pv[nt] = (f32x4){0.f, 0.f, 0.f, 0.f};

  const int nch = ((tile - sl) >> 3) + 1;
  const int nhalf = nch * 2;
  int kb32 = sl * 64;

  bf16x8 ckf0[2], ckf1[2], nkf0[2], nkf1[2];
  float4 ck2[2], cik[2], nk2[2], nik[2];
  #pragma unroll
  for (int tt = 0; tt < 2; ++tt){
    const int kbase = kb32 + 16 * tt;
    ckf0[tt] = *(const bf16x8*)&Kh[(size_t)(kbase + col) * HD + quad * 8];
    ckf1[tt] = *(const bf16x8*)&Kh[(size_t)(kbase + col) * HD + 32 + quad * 8];
    ck2[tt]  = *(const float4*)&k2s[kbase + quad * 4];
    cik[tt]  = *(const float4*)&iks[kbase + quad * 4];
  }

  for (int i = 0; i < nhalf; ++i){
    const int nkb32 = (i & 1) ? (kb32 + 512 - 32) : (kb32 + 32);
    const bool have_next = (i + 1 < nhalf);
    if (have_next){
      #pragma unroll
      for (int tt = 0; tt < 2; ++tt){
        const int kbase = nkb32 + 16 * tt;
        nkf0[tt] = *(const bf16x8*)&Kh[(size_t)(kbase + col) * HD + quad * 8];
        nkf1[tt] = *(const bf16x8*)&Kh[(size_t)(kbase + col) * HD + 32 + quad * 8];
        nk2[tt]  = *(const float4*)&k2s[kbase + quad * 4];
        nik[tt]  = *(const float4*)&iks[kbase + quad * 4];
      }
    }

    unsigned int tlo[2], thi[2];
    #pragma unroll
    for (int tt = 0; tt < 2; ++tt){
      const int kbase = kb32 + 16 * tt;
      f32x4 s = (f32x4){0.f, 0.f, 0.f, 0.f};
      s = __builtin_amdgcn_mfma_f32_16x16x32_bf16(ckf0[tt], qf0, s, 0, 0, 0);
      s = __builtin_amdgcn_mfma_f32_16x16x32_bf16(ckf1[tt], qf1, s, 0, 0, 0);
      unsigned short pb[4];
      #pragma unroll
      for (int r = 0; r < 4; ++r){
        float k2 = (r == 0) ? ck2[tt].x : (r == 1) ? ck2[tt].y : (r == 2) ? ck2[tt].z : ck2[tt].w;
        float ik = (r == 0) ? cik[tt].x : (r == 1) ? cik[tt].y : (r == 2) ? cik[tt].z : cik[tt].w;
        float diff2 = fmaxf(q2 + k2 - 2.f * s[r], 0.f);
        float u = fmaxf(diff2 * cq * ik, 1e-7f);
        float z = 1.f + u + sqrtf(u * (u + 2.f));
        float dist = __logf(z);
        float wv = __expf(-e_tau * dist - gamv);
        int key = kbase + quad * 4 + r;
        if (key > qmax) wv = 0.f;
        pb[r] = f2bf(wv);
      }
      tlo[tt] = (unsigned int)pb[0] | ((unsigned int)pb[1] << 16);
      thi[tt] = (unsigned int)pb[2] | ((unsigned int)pb[3] << 16);
    }
    unsigned int a0 = (unsigned int)__shfl((int)tlo[0], srcA, 64);
    unsigned int a1 = (unsigned int)__shfl((int)tlo[1], srcA, 64);
    unsigned int b0 = (unsigned int)__shfl((int)thi[0], srcA, 64);
    unsigned int b1 = (unsigned int)__shfl((int)thi[1], srcA, 64);
    unsigned int c0 = (unsigned int)__shfl((int)tlo[0], srcB, 64);
    unsigned int c1 = (unsigned int)__shfl((int)tlo[1], srcB, 64);
    unsigned int d0 = (unsigned int)__shfl((int)thi[0], srcB, 64);
    unsigned int d1 = (unsigned int)__shfl((int)thi[1], srcB, 64);
    union { uint4 u; bf16x8 v; } pw;
    pw.u.x = tsel ? a1 : a0;
    pw.u.y = tsel ? b1 : b0;
    pw.u.z = tsel ? c1 : c0;
    pw.u.w = tsel ? d1 : d0;
    #pragma unroll
    for (int nt = 0; nt < 5; ++nt){
      bf16x8 vf = *(const bf16x8*)&VTh[(size_t)(16 * nt + col) * SEQ + kb32 + quad * 8];
      pv[nt] = __builtin_amdgcn_mfma_f32_16x16x32_bf16(pw.v, vf, pv[nt], 0, 0, 0);
    }

    if (have_next){
      #pragma unroll
      for (int tt = 0; tt < 2; ++tt){
        ckf0[tt] = nkf0[tt]; ckf1[tt] = nkf1[tt];
        ck2[tt] = nk2[tt];   cik[tt] = nik[tt];
      }
    }
    kb32 = nkb32;
  }

  if (use_part){
    uint2* slot = (uint2*)big + (size_t)((((h * 32 + tile) * 8) + sl) * 4 + w) * 320;
    #pragma unroll
    for (int nt = 0; nt < 5; ++nt){
      uint2 pk;
      pk.x = (unsigned int)f2bf(pv[nt][0]) | ((unsigned int)f2bf(pv[nt][1]) << 16);
      pk.y = (unsigned int)f2bf(pv[nt][2]) | ((unsigned int)f2bf(pv[nt][3]) << 16);
      slot[nt * 64 + lane] = pk;
    }
  } else {
    #pragma unroll
    for (int r = 0; r < 4; ++r){
      float* row = big + ((size_t)h * SEQ + q0 + quad * 4 + r) * 80;
      #pragma unroll
      for (int nt = 0; nt < 5; ++nt)
        atomicAdd(&row[16 * nt + col], pv[nt][r]);
    }
  }
}

// K3b: bf16-slice-sum (4 waves, <=2 serial reads each) + LDS reduce + gyromidpoint.
// Grid (128, H), 256 threads.
__global__ __launch_bounds__(256) void attn_fin_kernel(
    const float* __restrict__ big, int use_part,
    float* __restrict__ out, float beta_scale)
{
  const int h = blockIdx.y, tile16 = blockIdx.x;
  const int t = threadIdx.x;
  const int w = t >> 6, lane = t & 63;
  const int col = lane & 15, quad = lane >> 4;
  const int q0 = tile16 * 16;

  __shared__ float red[4][64][20];

  f32x4 pv[5];
  #pragma unroll
  for (int nt = 0; nt < 5; ++nt) pv[nt] = (f32x4){0.f, 0.f, 0.f, 0.f};

  if (use_part){
    const int st = tile16 >> 2, wq = tile16 & 3;
    const int nv = (st + 1 < 8) ? st + 1 : 8;
    for (int sl = w; sl < nv; sl += 4){
      const uint2* slot = (const uint2*)big +
          (size_t)((((h * 32 + st) * 8) + sl) * 4 + wq) * 320;
      #pragma unroll
      for (int nt = 0; nt < 5; ++nt){
        uint2 v = slot[nt * 64 + lane];
        pv[nt][0] += bf2f((unsigned short)(v.x & 0xffffu));
        pv[nt][1] += bf2f((unsigned short)(v.x >> 16));
        pv[nt][2] += bf2f((unsigned short)(v.y & 0xffffu));
        pv[nt][3] += bf2f((unsigned short)(v.y >> 16));
      }
    }
  } else if (w == 0){
    #pragma unroll
    for (int nt = 0; nt < 5; ++nt)
      #pragma unroll
      for (int r = 0; r < 4; ++r)
        pv[nt][r] = big[((size_t)h * SEQ + q0 + quad * 4 + r) * 80 + 16 * nt + col];
  }

  #pragma unroll
  for (int nt = 0; nt < 5; ++nt)
    *(float4*)&red[w][lane][nt * 4] = (float4){pv[nt][0], pv[nt][1], pv[nt][2], pv[nt][3]};
  __syncthreads();

  if (t < 64){
    #pragma unroll
    for (int nt = 0; nt < 5; ++nt){
      float4 a = *(const float4*)&red[0][t][nt * 4];
      float4 b = *(const float4*)&red[1][t][nt * 4];
      float4 c = *(const float4*)&red[2][t][nt * 4];
      float4 d = *(const float4*)&red[3][t][nt * 4];
      pv[nt][0] = a.x + b.x + c.x + d.x;
      pv[nt][1] = a.y + b.y + c.y + d.y;
      pv[nt][2] = a.z + b.z + c.z + d.z;
      pv[nt][3] = a.w + b.w + c.w + d.w;
    }
    #pragma unroll
    for (int r = 0; r < 4; ++r){
      float den = __shfl(pv[4][r], quad * 16, 64);
      den = fmaxf(den, EPSF);
      float inv_den = 1.f / den;
      float g[4];
      float gsq = 0.f;
      #pragma unroll
      for (int nt = 0; nt < 4; ++nt){ g[nt] = pv[nt][r] * inv_den; gsq += g[nt] * g[nt]; }
      #pragma unroll
      for (int m = 8; m >= 1; m >>= 1) gsq += __shfl_xor(gsq, m, 64);
      float gn = fmaxf(sqrtf(gsq), EPSF);
      float x = fminf(gn, 1.f - 1e-7f);
      float tt2 = x / (1.f + sqrtf(1.f - x * x));
      float scl = (tt2 / gn) * beta_scale;
      const int q = q0 + quad * 4 + r;
      #pragma unroll
      for (int nt = 0; nt < 4; ++nt)
        out[(size_t)q * EDIM + h * HD + 16 * nt + col] = g[nt] * scl;
    }
  }
}

extern "C" void kernel_launch(void* const* d_in, const int* in_sizes, int n_in,
                              void* d_out, int out_size, void* d_ws, size_t ws_size,
                              hipStream_t stream){
  const void* Xq  = d_in[0];
  const void* Xk  = d_in[1];
  const void* Xv  = d_in[2];
  const void* Wq  = d_in[3];
  const void* Wk  = d_in[4];
  const void* Wv  = d_in[5];
  const void* Bq  = d_in[6];
  const void* Bk  = d_in[7];
  const void* Bv  = d_in[8];
  const void* tau = d_in[9];
  const void* gam = d_in[10];

  float* wsf   = (float*)d_ws;
  float* zn    = wsf + ZN_OFF;
  float* stats = wsf + STATS_OFF;
  float* cqs   = wsf + CQ_OFF;
  float* iks   = wsf + IK_OFF;
  unsigned short* u16b = (unsigned short*)(wsf + U16_OFF);
  unsigned short* WT   = u16b + WT_U16;
  unsigned short* qkvb = u16b + QKVB_U16;
  unsigned short* VT   = u16b + VT_U16;
  float* big   = wsf + BIG_OFF;

  const int use_part =
      (ws_size >= (size_t)BIG_OFF * sizeof(float) + (size_t)PART_U16S * 2) ? 1 : 0;

  unsigned short* Qb = qkvb;
  unsigned short* Kb = qkvb + (size_t)H * SEQ * HD;
  float* q2s = stats;
  float* k2s = stats + (size_t)H * SEQ;
  const unsigned short* qprobe = (const unsigned short*)Xq;

  double lb1 = lgamma(EDIM / 2.0) + lgamma(0.5) - lgamma(EDIM / 2.0 + 0.5);
  double lb2 = lgamma(HD / 2.0)   + lgamma(0.5) - lgamma(HD / 2.0 + 0.5);
  float beta_scale = (float)exp(lb1 - lb2);

  if (!use_part)
    hipMemsetAsync(big, 0, (size_t)ACC_FLOATS * sizeof(float), stream);
  wcvt_kernel<<<dim3(64, 3), dim3(256), 0, stream>>>(Wq, Wk, Wv, qprobe, WT, zn);
  hlinear_kernel<<<dim3(SEQ / 16, 3), dim3(256), 0, stream>>>(
      Xq, Xk, Xv, WT, Bq, Bk, Bv, zn, qkvb, stats, cqs, iks, VT);
  attn_kernel<<<dim3(32 * 8 * 4, H), dim3(64), 0, stream>>>(
      Qb, Kb, VT, q2s, k2s, cqs, iks, tau, gam, qprobe, big, use_part);
  attn_fin_kernel<<<dim3(128, H), dim3(256), 0, stream>>>(
      big, use_part, (float*)d_out, beta_scale);
}

// Round 22
// 203.063 us; speedup vs baseline: 1.0602x; 1.0170x over previous
//
#include <hip/hip_runtime.h>
#include <cmath>

#define H 8
#define SEQ 2048
#define EDIM 512
#define HD 64
#define EPSF 1e-15f

typedef short bf16x8 __attribute__((ext_vector_type(8)));
typedef float f32x4 __attribute__((ext_vector_type(4)));

// workspace layout (float offsets; 16B-aligned)
#define ZN_OFF    16                                // 8 bi-slots x 3 x EDIM partial sums
#define STATS_OFF (ZN_OFF + 24 * EDIM)              // 3*H*SEQ fp32 (rounded q2/k2/v2)
#define CQ_OFF    (STATS_OFF + 3 * H * SEQ)         // H*SEQ: 2/(1-q2)
#define IK_OFF    (CQ_OFF + H * SEQ)                // H*SEQ: 1/(1-k2)
#define PX2_OFF   (IK_OFF + H * SEQ)                // 3*128*2*16 fp32 partial row-x2
#define U16_OFF   (PX2_OFF + 12288 + 16)
#define WT_U16    0
#define QKVB_U16  (WT_U16 + 3 * EDIM * EDIM)
#define VT_U16    (QKVB_U16 + 3 * SEQ * EDIM)
#define U16_TOTAL (VT_U16 + H * 80 * SEQ)
#define BIG_OFF   (U16_OFF + U16_TOTAL / 2 + 16)    // partC (12.6MB) then attn part (21MB)
#define PART_U16S (8 * 32 * 8 * 4 * 1280)           // 10,485,760 u16 = 21 MB
#define ACC_FLOATS  (H * SEQ * 80)

__device__ __forceinline__ float bf2f(unsigned short u){
  union { unsigned int i; float f; } v; v.i = ((unsigned int)u) << 16; return v.f;
}
__device__ __forceinline__ unsigned short f2bf(float f){
  union { float f; unsigned int i; } v; v.f = f;
  unsigned int x = v.i;
  unsigned int r = (x + 0x7fffu + ((x >> 16) & 1u)) >> 16;
  return (unsigned short)r;
}

// inline dtype detect (fp32 data bf16-decodes to huge magnitudes w.p. ~1)
__device__ __forceinline__ int detect_f32(const unsigned short* __restrict__ q){
  const int l = threadIdx.x & 63;
  float mx = 0.f;
  #pragma unroll
  for (int j = 0; j < 4; ++j) mx = fmaxf(mx, fabsf(bf2f(q[l * 4 + j])));
  #pragma unroll
  for (int m = 32; m >= 1; m >>= 1) mx = fmaxf(mx, __shfl_xor(mx, m, 64));
  return mx > 1000.f;
}

// P1: W -> WT bf16 [p][o][i] (transpose) + per-bi partial column sumsq (no atomics).
__global__ __launch_bounds__(256) void wcvt_kernel(
    const void* __restrict__ Wq, const void* __restrict__ Wk, const void* __restrict__ Wv,
    const unsigned short* __restrict__ qprobe,
    unsigned short* __restrict__ WT, float* __restrict__ zn)
{
  const int p = blockIdx.y;
  const int bi = blockIdx.x >> 3, bo = blockIdx.x & 7;
  const void* W = (p == 0) ? Wq : ((p == 1) ? Wk : Wv);
  const int t = threadIdx.x;
  const int isf32 = detect_f32(qprobe);
  __shared__ float tile[64][65];

  #pragma unroll
  for (int j = 0; j < 16; ++j){
    int idx = t + 256 * j;
    int il = idx >> 6, ol = idx & 63;
    float val;
    if (isf32) val = ((const float*)W)[(size_t)(bi * 64 + il) * EDIM + bo * 64 + ol];
    else       val = bf2f(((const unsigned short*)W)[(size_t)(bi * 64 + il) * EDIM + bo * 64 + ol]);
    tile[il][ol] = val;
  }
  __syncthreads();
  if (t < 64){
    float s = 0.f;
    #pragma unroll 8
    for (int i = 0; i < 64; ++i){ float v = tile[i][t]; s += v * v; }
    zn[((size_t)(bi * 3 + p)) * EDIM + bo * 64 + t] = s;
  }
  #pragma unroll
  for (int j = 0; j < 16; ++j){
    int idx = t + 256 * j;
    int ol = idx >> 6, il = idx & 63;
    WT[((size_t)p * EDIM + bo * 64 + ol) * EDIM + bi * 64 + il] = f2bf(tile[il][ol]);
  }
}

// K1a: projection GEMM, K-SPLIT: block = 16 rows x 512 cols x half-K (8 ks iters,
// register double-buffered). 768 blocks = 3/CU exact. NO LDS. Writes bf16 partial
// C (coalesced) + fp32 partial row-x2.
__global__ __launch_bounds__(256) void hlin_gemm_kernel(
    const void* __restrict__ Xq, const void* __restrict__ Xk, const void* __restrict__ Xv,
    const unsigned short* __restrict__ WT, const unsigned short* __restrict__ qprobe,
    unsigned short* __restrict__ partC, float* __restrict__ partX2)
{
  const int p = blockIdx.y;
  const int rg = blockIdx.x >> 1;
  const int kslice = blockIdx.x & 1;
  const void* X = (p == 0) ? Xq : ((p == 1) ? Xk : Xv);
  const int r0 = rg * 16;
  const int t  = threadIdx.x;
  const int w = t >> 6, lane = t & 63;
  const int col = lane & 15, quad = lane >> 4;
  const int isf32 = detect_f32(qprobe);
  const int koff = kslice * 256;   // element offset of this k-half

  const unsigned short* WTb = WT + ((size_t)p * EDIM + w * 128 + col) * EDIM + koff;
  const float* Xf = (const float*)X + (size_t)(r0 + col) * EDIM + koff;
  const unsigned short* Xh = (const unsigned short*)X + (size_t)(r0 + col) * EDIM + koff;

  f32x4 acc[8];
  #pragma unroll
  for (int nt = 0; nt < 8; ++nt) acc[nt] = (f32x4){0.f, 0.f, 0.f, 0.f};
  float x2part = 0.f;

  bf16x8 caf, naf;
  bf16x8 cbf[8], nbf[8];
  {
    if (isf32){
      float4 xa = *(const float4*)&Xf[quad * 8];
      float4 xb = *(const float4*)&Xf[quad * 8 + 4];
      float xv[8] = {xa.x, xa.y, xa.z, xa.w, xb.x, xb.y, xb.z, xb.w};
      #pragma unroll
      for (int j = 0; j < 8; ++j){ caf[j] = (short)f2bf(xv[j]); x2part += xv[j] * xv[j]; }
    } else {
      caf = *(const bf16x8*)&Xh[quad * 8];
      #pragma unroll
      for (int j = 0; j < 8; ++j){ float xv = bf2f((unsigned short)caf[j]); x2part += xv * xv; }
    }
    #pragma unroll
    for (int nt = 0; nt < 8; ++nt)
      cbf[nt] = *(const bf16x8*)&WTb[(size_t)nt * 16 * EDIM + quad * 8];
  }

  for (int ks = 0; ks < 8; ++ks){
    if (ks + 1 < 8){
      const int off = (ks + 1) * 32 + quad * 8;
      if (isf32){
        float4 xa = *(const float4*)&Xf[off];
        float4 xb = *(const float4*)&Xf[off + 4];
        float xv[8] = {xa.x, xa.y, xa.z, xa.w, xb.x, xb.y, xb.z, xb.w};
        #pragma unroll
        for (int j = 0; j < 8; ++j){ naf[j] = (short)f2bf(xv[j]); x2part += xv[j] * xv[j]; }
      } else {
        naf = *(const bf16x8*)&Xh[off];
        #pragma unroll
        for (int j = 0; j < 8; ++j){ float xv = bf2f((unsigned short)naf[j]); x2part += xv * xv; }
      }
      #pragma unroll
      for (int nt = 0; nt < 8; ++nt)
        nbf[nt] = *(const bf16x8*)&WTb[(size_t)nt * 16 * EDIM + off];
    }
    #pragma unroll
    for (int nt = 0; nt < 8; ++nt)
      acc[nt] = __builtin_amdgcn_mfma_f32_16x16x32_bf16(caf, cbf[nt], acc[nt], 0, 0, 0);
    if (ks + 1 < 8){
      caf = naf;
      #pragma unroll
      for (int nt = 0; nt < 8; ++nt) cbf[nt] = nbf[nt];
    }
  }
  // row (r0+col) partial sumsq over this k-half
  x2part += __shfl_xor(x2part, 16, 64);
  x2part += __shfl_xor(x2part, 32, 64);

  const size_t base = ((size_t)(p * 128 + rg) * 2 + kslice) * 8192;
  #pragma unroll
  for (int nt = 0; nt < 8; ++nt)
    #pragma unroll
    for (int r = 0; r < 4; ++r)
      partC[base + (size_t)(quad * 4 + r) * 512 + w * 128 + nt * 16 + col] = f2bf(acc[nt][r]);
  if (w == 0 && quad == 0)
    partX2[((size_t)(p * 128 + rg) * 2 + kslice) * 16 + col] = x2part;
}

// K1b: combine k-halves + transform + normalization tail (verbatim R21 tail).
__global__ __launch_bounds__(256) void hlin_fin_kernel(
    const unsigned short* __restrict__ partC, const float* __restrict__ partX2,
    const void* __restrict__ Bq, const void* __restrict__ Bk, const void* __restrict__ Bv,
    const float* __restrict__ znacc, const unsigned short* __restrict__ qprobe,
    unsigned short* __restrict__ qkvb, float* __restrict__ stats,
    float* __restrict__ cqs, float* __restrict__ iks,
    unsigned short* __restrict__ VT)
{
  const int p = blockIdx.y;
  const void* Bb = (p == 0) ? Bq : ((p == 1) ? Bk : Bv);
  const int rg = blockIdx.x;
  const int r0 = rg * 16;
  const int t  = threadIdx.x;
  const int w = t >> 6, lane = t & 63;
  const int col = lane & 15, quad = lane >> 4;
  const int isf32 = detect_f32(qprobe);

  __shared__ float smem[16 * EDIM];
  __shared__ float sw2[16];

  const size_t base0 = ((size_t)(p * 128 + rg) * 2 + 0) * 8192;
  const size_t base1 = base0 + 8192;

  f32x4 acc[8];
  #pragma unroll
  for (int nt = 0; nt < 8; ++nt)
    #pragma unroll
    for (int r = 0; r < 4; ++r){
      const size_t idx = (size_t)(quad * 4 + r) * 512 + w * 128 + nt * 16 + col;
      acc[nt][r] = bf2f(partC[base0 + idx]) + bf2f(partC[base1 + idx]);
    }

  float lamr[4], lm1[4];
  #pragma unroll
  for (int r = 0; r < 4; ++r){
    const int row = quad * 4 + r;
    float x2r = partX2[((size_t)(p * 128 + rg) * 2 + 0) * 16 + row] +
                partX2[((size_t)(p * 128 + rg) * 2 + 1) * 16 + row];
    lamr[r] = 2.f / (1.f - x2r);
    lm1[r] = lamr[r] - 1.f;
  }
  #pragma unroll
  for (int nt = 0; nt < 8; ++nt){
    const int n = w * 128 + nt * 16 + col;
    float zsum = 0.f;
    #pragma unroll
    for (int bi = 0; bi < 8; ++bi)
      zsum += znacc[((size_t)(bi * 3 + p)) * EDIM + n];
    float znv = fmaxf(sqrtf(zsum), EPSF);
    float rb;
    if (isf32) rb = ((const float*)Bb)[n];
    else       rb = bf2f(((const unsigned short*)Bb)[n]);
    float e2r = __expf(2.f * rb);
    float ie2r = 1.f / e2r;
    float ch = 0.5f * (e2r + ie2r), sh = 0.5f * (e2r - ie2r);
    float izn = 1.f / znv;
    float tz = 2.f * znv;
    #pragma unroll
    for (int r = 0; r < 4; ++r){
      float a = (acc[nt][r] * lamr[r] * izn) * ch - lm1[r] * sh;
      float b = a + sqrtf(a * a + 1.f);
      float tt = __expf(tz * __logf(b));
      smem[(quad * 4 + r) * EDIM + n] = 0.5f * (tt - 1.f / tt);
    }
  }
  __syncthreads();

  {
    int row = t >> 4, l = t & 15;
    float s = 0.f;
    for (int o = l; o < EDIM; o += 16){ float wv = smem[row * EDIM + o]; s += wv * wv; }
    #pragma unroll
    for (int m = 8; m >= 1; m >>= 1) s += __shfl_xor(s, m, 16);
    if (l == 0) sw2[row] = s;
  }
  __syncthreads();

  const int o0 = 2 * t;
  const int h0 = t >> 5;
  const int d0 = o0 & 63;
  const int l5 = t & 31;
  #pragma unroll
  for (int rr = 0; rr < 16; ++rr){
    float inv = 1.f / (1.f + sqrtf(1.f + sw2[rr]));
    unsigned short b0 = f2bf(smem[rr * EDIM + o0] * inv);
    unsigned short b1 = f2bf(smem[rr * EDIM + o0 + 1] * inv);
    float r0v = bf2f(b0), r1v = bf2f(b1);
    int s = r0 + rr;
    unsigned int* dst = (unsigned int*)&qkvb[(((size_t)p * H + h0) * SEQ + s) * HD + d0];
    *dst = (unsigned int)b0 | ((unsigned int)b1 << 16);
    float ss = r0v * r0v + r1v * r1v;
    #pragma unroll
    for (int m = 16; m >= 1; m >>= 1) ss += __shfl_xor(ss, m, 64);
    if (p == 2){
      float lam = 2.f / (1.f - ss);
      VT[((size_t)h0 * 80 + d0) * SEQ + s]     = f2bf(r0v * lam);
      VT[((size_t)h0 * 80 + d0 + 1) * SEQ + s] = f2bf(r1v * lam);
      if (l5 < 16)
        VT[((size_t)h0 * 80 + 64 + l5) * SEQ + s] = (l5 == 0) ? f2bf(lam - 1.f) : 0;
    }
    if (l5 == 0){
      stats[((size_t)p * H + h0) * SEQ + s] = ss;
      if (p == 0) cqs[(size_t)h0 * SEQ + s] = 2.f / (1.f - ss);
      if (p == 1) iks[(size_t)h0 * SEQ + s] = 1.f / (1.f - ss);
    }
  }
}

// K3a: attention — frozen R21 best: 1-wave blocks, LPT, pipelined body, bf16 partials.
__global__ __launch_bounds__(64) void attn_kernel(
    const unsigned short* __restrict__ Qb, const unsigned short* __restrict__ Kb,
    const unsigned short* __restrict__ VT,
    const float* __restrict__ q2s_all, const float* __restrict__ k2s_all,
    const float* __restrict__ cqs_all, const float* __restrict__ iks_all,
    const void* __restrict__ tau, const void* __restrict__ gam,
    const unsigned short* __restrict__ qprobe,
    float* __restrict__ big, int use_part)
{
  const int h  = blockIdx.y;
  const int tile = 31 - (blockIdx.x >> 5);
  const int sl = (blockIdx.x >> 2) & 7;
  const int w  = blockIdx.x & 3;
  if (sl > tile) return;
  const int lane = threadIdx.x;
  const int col = lane & 15, quad = lane >> 4;
  const int q0 = tile * 64 + w * 16;

  const unsigned short* Qh  = Qb + (size_t)h * SEQ * HD;
  const unsigned short* Kh  = Kb + (size_t)h * SEQ * HD;
  const unsigned short* VTh = VT + (size_t)h * 80 * SEQ;
  const float* q2s = q2s_all + (size_t)h * SEQ;
  const float* k2s = k2s_all + (size_t)h * SEQ;
  const float* cqs = cqs_all + (size_t)h * SEQ;
  const float* iks = iks_all + (size_t)h * SEQ;

  const int isf32 = detect_f32(qprobe);
  float tauv, gamv;
  if (isf32){ tauv = ((const float*)tau)[0]; gamv = ((const float*)gam)[0]; }
  else      { tauv = bf2f(((const unsigned short*)tau)[0]);
              gamv = bf2f(((const unsigned short*)gam)[0]); }
  const float e_tau = __expf(tauv);

  const int srcA = ((quad & 1) * 2) * 16 + col;
  const int srcB = srcA + 16;
  const int tsel = quad >> 1;

  bf16x8 qf0 = *(const bf16x8*)&Qh[(size_t)(q0 + col) * HD + quad * 8];
  bf16x8 qf1 = *(const bf16x8*)&Qh[(size_t)(q0 + col) * HD + 32 + quad * 8];
  const float q2 = q2s[q0 + col];
  const float cq = cqs[q0 + col];
  const int qmax = q0 + col;

  f32x4 pv[5];
  #pragma unroll
  for (int nt = 0; nt < 5; ++nt) pv[nt] = (f32x4){0.f, 0.f, 0.f, 0.f};

  const int nch = ((tile - sl) >> 3) + 1;
  const int nhalf = nch * 2;
  int kb32 = sl * 64;

  bf16x8 ckf0[2], ckf1[2], nkf0[2], nkf1[2];
  float4 ck2[2], cik[2], nk2[2], nik[2];
  #pragma unroll
  for (int tt = 0; tt < 2; ++tt){
    const int kbase = kb32 + 16 * tt;
    ckf0[tt] = *(const bf16x8*)&Kh[(size_t)(kbase + col) * HD + quad * 8];
    ckf1[tt] = *(const bf16x8*)&Kh[(size_t)(kbase + col) * HD + 32 + quad * 8];
    ck2[tt]  = *(const float4*)&k2s[kbase + quad * 4];
    cik[tt]  = *(const float4*)&iks[kbase + quad * 4];
  }

  for (int i = 0; i < nhalf; ++i){
    const int nkb32 = (i & 1) ? (kb32 + 512 - 32) : (kb32 + 32);
    const bool have_next = (i + 1 < nhalf);
    if (have_next){
      #pragma unroll
      for (int tt = 0; tt < 2; ++tt){
        const int kbase = nkb32 + 16 * tt;
        nkf0[tt] = *(const bf16x8*)&Kh[(size_t)(kbase + col) * HD + quad * 8];
        nkf1[tt] = *(const bf16x8*)&Kh[(size_t)(kbase + col) * HD + 32 + quad * 8];
        nk2[tt]  = *(const float4*)&k2s[kbase + quad * 4];
        nik[tt]  = *(const float4*)&iks[kbase + quad * 4];
      }
    }

    unsigned int tlo[2], thi[2];
    #pragma unroll
    for (int tt = 0; tt < 2; ++tt){
      const int kbase = kb32 + 16 * tt;
      f32x4 s = (f32x4){0.f, 0.f, 0.f, 0.f};
      s = __builtin_amdgcn_mfma_f32_16x16x32_bf16(ckf0[tt], qf0, s, 0, 0, 0);
      s = __builtin_amdgcn_mfma_f32_16x16x32_bf16(ckf1[tt], qf1, s, 0, 0, 0);
      unsigned short pb[4];
      #pragma unroll
      for (int r = 0; r < 4; ++r){
        float k2 = (r == 0) ? ck2[tt].x : (r == 1) ? ck2[tt].y : (r == 2) ? ck2[tt].z : ck2[tt].w;
        float ik = (r == 0) ? cik[tt].x : (r == 1) ? cik[tt].y : (r == 2) ? cik[tt].z : cik[tt].w;
        float diff2 = fmaxf(q2 + k2 - 2.f * s[r], 0.f);
        float u = fmaxf(diff2 * cq * ik, 1e-7f);
        float z = 1.f + u + sqrtf(u * (u + 2.f));
        float dist = __logf(z);
        float wv = __expf(-e_tau * dist - gamv);
        int key = kbase + quad * 4 + r;
        if (key > qmax) wv = 0.f;
        pb[r] = f2bf(wv);
      }
      tlo[tt] = (unsigned int)pb[0] | ((unsigned int)pb[1] << 16);
      thi[tt] = (unsigned int)pb[2] | ((unsigned int)pb[3] << 16);
    }
    unsigned int a0 = (unsigned int)__shfl((int)tlo[0], srcA, 64);
    unsigned int a1 = (unsigned int)__shfl((int)tlo[1], srcA, 64);
    unsigned int b0 = (unsigned int)__shfl((int)thi[0], srcA, 64);
    unsigned int b1 = (unsigned int)__shfl((int)thi[1], srcA, 64);
    unsigned int c0 = (unsigned int)__shfl((int)tlo[0], srcB, 64);
    unsigned int c1 = (unsigned int)__shfl((int)tlo[1], srcB, 64);
    unsigned int d0 = (unsigned int)__shfl((int)thi[0], srcB, 64);
    unsigned int d1 = (unsigned int)__shfl((int)thi[1], srcB, 64);
    union { uint4 u; bf16x8 v; } pw;
    pw.u.x = tsel ? a1 : a0;
    pw.u.y = tsel ? b1 : b0;
    pw.u.z = tsel ? c1 : c0;
    pw.u.w = tsel ? d1 : d0;
    #pragma unroll
    for (int nt = 0; nt < 5; ++nt){
      bf16x8 vf = *(const bf16x8*)&VTh[(size_t)(16 * nt + col) * SEQ + kb32 + quad * 8];
      pv[nt] = __builtin_amdgcn_mfma_f32_16x16x32_bf16(pw.v, vf, pv[nt], 0, 0, 0);
    }

    if (have_next){
      #pragma unroll
      for (int tt = 0; tt < 2; ++tt){
        ckf0[tt] = nkf0[tt]; ckf1[tt] = nkf1[tt];
        ck2[tt] = nk2[tt];   cik[tt] = nik[tt];
      }
    }
    kb32 = nkb32;
  }

  if (use_part){
    uint2* slot = (uint2*)big + (size_t)((((h * 32 + tile) * 8) + sl) * 4 + w) * 320;
    #pragma unroll
    for (int nt = 0; nt < 5; ++nt){
      uint2 pk;
      pk.x = (unsigned int)f2bf(pv[nt][0]) | ((unsigned int)f2bf(pv[nt][1]) << 16);
      pk.y = (unsigned int)f2bf(pv[nt][2]) | ((unsigned int)f2bf(pv[nt][3]) << 16);
      slot[nt * 64 + lane] = pk;
    }
  } else {
    #pragma unroll
    for (int r = 0; r < 4; ++r){
      float* row = big + ((size_t)h * SEQ + q0 + quad * 4 + r) * 80;
      #pragma unroll
      for (int nt = 0; nt < 5; ++nt)
        atomicAdd(&row[16 * nt + col], pv[nt][r]);
    }
  }
}

// K3b: bf16-slice-sum + LDS reduce + gyromidpoint. Grid (128, H), 256 threads.
__global__ __launch_bounds__(256) void attn_fin_kernel(
    const float* __restrict__ big, int use_part,
    float* __restrict__ out, float beta_scale)
{
  const int h = blockIdx.y, tile16 = blockIdx.x;
  const int t = threadIdx.x;
  const int w = t >> 6, lane = t & 63;
  const int col = lane & 15, quad = lane >> 4;
  const int q0 = tile16 * 16;

  __shared__ float red[4][64][20];

  f32x4 pv[5];
  #pragma unroll
  for (int nt = 0; nt < 5; ++nt) pv[nt] = (f32x4){0.f, 0.f, 0.f, 0.f};

  if (use_part){
    const int st = tile16 >> 2, wq = tile16 & 3;
    const int nv = (st + 1 < 8) ? st + 1 : 8;
    for (int sl = w; sl < nv; sl += 4){
      const uint2* slot = (const uint2*)big +
          (size_t)((((h * 32 + st) * 8) + sl) * 4 + wq) * 320;
      #pragma unroll
      for (int nt = 0; nt < 5; ++nt){
        uint2 v = slot[nt * 64 + lane];
        pv[nt][0] += bf2f((unsigned short)(v.x & 0xffffu));
        pv[nt][1] += bf2f((unsigned short)(v.x >> 16));
        pv[nt][2] += bf2f((unsigned short)(v.y & 0xffffu));
        pv[nt][3] += bf2f((unsigned short)(v.y >> 16));
      }
    }
  } else if (w == 0){
    #pragma unroll
    for (int nt = 0; nt < 5; ++nt)
      #pragma unroll
      for (int r = 0; r < 4; ++r)
        pv[nt][r] = big[((size_t)h * SEQ + q0 + quad * 4 + r) * 80 + 16 * nt + col];
  }

  #pragma unroll
  for (int nt = 0; nt < 5; ++nt)
    *(float4*)&red[w][lane][nt * 4] = (float4){pv[nt][0], pv[nt][1], pv[nt][2], pv[nt][3]};
  __syncthreads();

  if (t < 64){
    #pragma unroll
    for (int nt = 0; nt < 5; ++nt){
      float4 a = *(const float4*)&red[0][t][nt * 4];
      float4 b = *(const float4*)&red[1][t][nt * 4];
      float4 c = *(const float4*)&red[2][t][nt * 4];
      float4 d = *(const float4*)&red[3][t][nt * 4];
      pv[nt][0] = a.x + b.x + c.x + d.x;
      pv[nt][1] = a.y + b.y + c.y + d.y;
      pv[nt][2] = a.z + b.z + c.z + d.z;
      pv[nt][3] = a.w + b.w + c.w + d.w;
    }
    #pragma unroll
    for (int r = 0; r < 4; ++r){
      float den = __shfl(pv[4][r], quad * 16, 64);
      den = fmaxf(den, EPSF);
      float inv_den = 1.f / den;
      float g[4];
      float gsq = 0.f;
      #pragma unroll
      for (int nt = 0; nt < 4; ++nt){ g[nt] = pv[nt][r] * inv_den; gsq += g[nt] * g[nt]; }
      #pragma unroll
      for (int m = 8; m >= 1; m >>= 1) gsq += __shfl_xor(gsq, m, 64);
      float gn = fmaxf(sqrtf(gsq), EPSF);
      float x = fminf(gn, 1.f - 1e-7f);
      float tt2 = x / (1.f + sqrtf(1.f - x * x));
      float scl = (tt2 / gn) * beta_scale;
      const int q = q0 + quad * 4 + r;
      #pragma unroll
      for (int nt = 0; nt < 4; ++nt)
        out[(size_t)q * EDIM + h * HD + 16 * nt + col] = g[nt] * scl;
    }
  }
}

extern "C" void kernel_launch(void* const* d_in, const int* in_sizes, int n_in,
                              void* d_out, int out_size, void* d_ws, size_t ws_size,
                              hipStream_t stream){
  const void* Xq  = d_in[0];
  const void* Xk  = d_in[1];
  const void* Xv  = d_in[2];
  const void* Wq  = d_in[3];
  const void* Wk  = d_in[4];
  const void* Wv  = d_in[5];
  const void* Bq  = d_in[6];
  const void* Bk  = d_in[7];
  const void* Bv  = d_in[8];
  const void* tau = d_in[9];
  const void* gam = d_in[10];

  float* wsf   = (float*)d_ws;
  float* zn    = wsf + ZN_OFF;
  float* stats = wsf + STATS_OFF;
  float* cqs   = wsf + CQ_OFF;
  float* iks   = wsf + IK_OFF;
  float* px2   = wsf + PX2_OFF;
  unsigned short* u16b = (unsigned short*)(wsf + U16_OFF);
  unsigned short* WT   = u16b + WT_U16;
  unsigned short* qkvb = u16b + QKVB_U16;
  unsigned short* VT   = u16b + VT_U16;
  float* big   = wsf + BIG_OFF;
  unsigned short* partC = (unsigned short*)big;   // reused before attn runs

  const int use_part =
      (ws_size >= (size_t)BIG_OFF * sizeof(float) + (size_t)PART_U16S * 2) ? 1 : 0;

  unsigned short* Qb = qkvb;
  unsigned short* Kb = qkvb + (size_t)H * SEQ * HD;
  float* q2s = stats;
  float* k2s = stats + (size_t)H * SEQ;
  const unsigned short* qprobe = (const unsigned short*)Xq;

  double lb1 = lgamma(EDIM / 2.0) + lgamma(0.5) - lgamma(EDIM / 2.0 + 0.5);
  double lb2 = lgamma(HD / 2.0)   + lgamma(0.5) - lgamma(HD / 2.0 + 0.5);
  float beta_scale = (float)exp(lb1 - lb2);

  wcvt_kernel<<<dim3(64, 3), dim3(256), 0, stream>>>(Wq, Wk, Wv, qprobe, WT, zn);
  hlin_gemm_kernel<<<dim3(256, 3), dim3(256), 0, stream>>>(
      Xq, Xk, Xv, WT, qprobe, partC, px2);
  hlin_fin_kernel<<<dim3(128, 3), dim3(256), 0, stream>>>(
      partC, px2, Bq, Bk, Bv, zn, qprobe, qkvb, stats, cqs, iks, VT);
  if (!use_part)
    hipMemsetAsync(big, 0, (size_t)ACC_FLOATS * sizeof(float), stream);
  attn_kernel<<<dim3(32 * 8 * 4, H), dim3(64), 0, stream>>>(
      Qb, Kb, VT, q2s, k2s, cqs, iks, tau, gam, qprobe, big, use_part);
  attn_fin_kernel<<<dim3(128, H), dim3(256), 0, stream>>>(
      big, use_part, (float*)d_out, beta_scale);
}

// Round 23
// 200.531 us; speedup vs baseline: 1.0736x; 1.0126x over previous
//
#include <hip/hip_runtime.h>
#include <cmath>

#define H 8
#define SEQ 2048
#define EDIM 512
#define HD 64
#define EPSF 1e-15f

typedef short bf16x8 __attribute__((ext_vector_type(8)));
typedef float f32x4 __attribute__((ext_vector_type(4)));

// workspace layout (float offsets; 16B-aligned)
#define ZN_OFF    16                                // 8 bi-slots x 3 x EDIM partial sums
#define STATS_OFF (ZN_OFF + 24 * EDIM)              // 3*H*SEQ fp32 (rounded q2/k2/v2)
#define CQ_OFF    (STATS_OFF + 3 * H * SEQ)         // H*SEQ: 2/(1-q2)
#define IK_OFF    (CQ_OFF + H * SEQ)                // H*SEQ: 1/(1-k2)
#define PX2_OFF   (IK_OFF + H * SEQ)                // 3*128*2*16 fp32 partial row-x2
#define U16_OFF   (PX2_OFF + 12288 + 16)
#define WT_U16    0
#define QKVB_U16  (WT_U16 + 3 * EDIM * EDIM)
#define VT_U16    (QKVB_U16 + 3 * SEQ * EDIM)
#define U16_TOTAL (VT_U16 + H * 80 * SEQ)
#define BIG_OFF   (U16_OFF + U16_TOTAL / 2 + 16)    // partC (12.6MB) then attn part (21MB)
#define PART_U16S (8 * 32 * 8 * 4 * 1280)           // 10,485,760 u16 = 21 MB
#define ACC_FLOATS  (H * SEQ * 80)

__device__ __forceinline__ float bf2f(unsigned short u){
  union { unsigned int i; float f; } v; v.i = ((unsigned int)u) << 16; return v.f;
}
__device__ __forceinline__ unsigned short f2bf(float f){
  union { float f; unsigned int i; } v; v.f = f;
  unsigned int x = v.i;
  unsigned int r = (x + 0x7fffu + ((x >> 16) & 1u)) >> 16;
  return (unsigned short)r;
}

// inline dtype detect (fp32 data bf16-decodes to huge magnitudes w.p. ~1)
__device__ __forceinline__ int detect_f32(const unsigned short* __restrict__ q){
  const int l = threadIdx.x & 63;
  float mx = 0.f;
  #pragma unroll
  for (int j = 0; j < 4; ++j) mx = fmaxf(mx, fabsf(bf2f(q[l * 4 + j])));
  #pragma unroll
  for (int m = 32; m >= 1; m >>= 1) mx = fmaxf(mx, __shfl_xor(mx, m, 64));
  return mx > 1000.f;
}

// P1: W -> WT bf16 [p][o][i] (transpose) + per-bi partial column sumsq (no atomics).
__global__ __launch_bounds__(256) void wcvt_kernel(
    const void* __restrict__ Wq, const void* __restrict__ Wk, const void* __restrict__ Wv,
    const unsigned short* __restrict__ qprobe,
    unsigned short* __restrict__ WT, float* __restrict__ zn)
{
  const int p = blockIdx.y;
  const int bi = blockIdx.x >> 3, bo = blockIdx.x & 7;
  const void* W = (p == 0) ? Wq : ((p == 1) ? Wk : Wv);
  const int t = threadIdx.x;
  const int isf32 = detect_f32(qprobe);
  __shared__ float tile[64][65];

  #pragma unroll
  for (int j = 0; j < 16; ++j){
    int idx = t + 256 * j;
    int il = idx >> 6, ol = idx & 63;
    float val;
    if (isf32) val = ((const float*)W)[(size_t)(bi * 64 + il) * EDIM + bo * 64 + ol];
    else       val = bf2f(((const unsigned short*)W)[(size_t)(bi * 64 + il) * EDIM + bo * 64 + ol]);
    tile[il][ol] = val;
  }
  __syncthreads();
  if (t < 64){
    float s = 0.f;
    #pragma unroll 8
    for (int i = 0; i < 64; ++i){ float v = tile[i][t]; s += v * v; }
    zn[((size_t)(bi * 3 + p)) * EDIM + bo * 64 + t] = s;
  }
  #pragma unroll
  for (int j = 0; j < 16; ++j){
    int idx = t + 256 * j;
    int ol = idx >> 6, il = idx & 63;
    WT[((size_t)p * EDIM + bo * 64 + ol) * EDIM + bi * 64 + il] = f2bf(tile[il][ol]);
  }
}

// K1a: projection GEMM, K-SPLIT (frozen R22).
__global__ __launch_bounds__(256) void hlin_gemm_kernel(
    const void* __restrict__ Xq, const void* __restrict__ Xk, const void* __restrict__ Xv,
    const unsigned short* __restrict__ WT, const unsigned short* __restrict__ qprobe,
    unsigned short* __restrict__ partC, float* __restrict__ partX2)
{
  const int p = blockIdx.y;
  const int rg = blockIdx.x >> 1;
  const int kslice = blockIdx.x & 1;
  const void* X = (p == 0) ? Xq : ((p == 1) ? Xk : Xv);
  const int r0 = rg * 16;
  const int t  = threadIdx.x;
  const int w = t >> 6, lane = t & 63;
  const int col = lane & 15, quad = lane >> 4;
  const int isf32 = detect_f32(qprobe);
  const int koff = kslice * 256;

  const unsigned short* WTb = WT + ((size_t)p * EDIM + w * 128 + col) * EDIM + koff;
  const float* Xf = (const float*)X + (size_t)(r0 + col) * EDIM + koff;
  const unsigned short* Xh = (const unsigned short*)X + (size_t)(r0 + col) * EDIM + koff;

  f32x4 acc[8];
  #pragma unroll
  for (int nt = 0; nt < 8; ++nt) acc[nt] = (f32x4){0.f, 0.f, 0.f, 0.f};
  float x2part = 0.f;

  bf16x8 caf, naf;
  bf16x8 cbf[8], nbf[8];
  {
    if (isf32){
      float4 xa = *(const float4*)&Xf[quad * 8];
      float4 xb = *(const float4*)&Xf[quad * 8 + 4];
      float xv[8] = {xa.x, xa.y, xa.z, xa.w, xb.x, xb.y, xb.z, xb.w};
      #pragma unroll
      for (int j = 0; j < 8; ++j){ caf[j] = (short)f2bf(xv[j]); x2part += xv[j] * xv[j]; }
    } else {
      caf = *(const bf16x8*)&Xh[quad * 8];
      #pragma unroll
      for (int j = 0; j < 8; ++j){ float xv = bf2f((unsigned short)caf[j]); x2part += xv * xv; }
    }
    #pragma unroll
    for (int nt = 0; nt < 8; ++nt)
      cbf[nt] = *(const bf16x8*)&WTb[(size_t)nt * 16 * EDIM + quad * 8];
  }

  for (int ks = 0; ks < 8; ++ks){
    if (ks + 1 < 8){
      const int off = (ks + 1) * 32 + quad * 8;
      if (isf32){
        float4 xa = *(const float4*)&Xf[off];
        float4 xb = *(const float4*)&Xf[off + 4];
        float xv[8] = {xa.x, xa.y, xa.z, xa.w, xb.x, xb.y, xb.z, xb.w};
        #pragma unroll
        for (int j = 0; j < 8; ++j){ naf[j] = (short)f2bf(xv[j]); x2part += xv[j] * xv[j]; }
      } else {
        naf = *(const bf16x8*)&Xh[off];
        #pragma unroll
        for (int j = 0; j < 8; ++j){ float xv = bf2f((unsigned short)naf[j]); x2part += xv * xv; }
      }
      #pragma unroll
      for (int nt = 0; nt < 8; ++nt)
        nbf[nt] = *(const bf16x8*)&WTb[(size_t)nt * 16 * EDIM + off];
    }
    #pragma unroll
    for (int nt = 0; nt < 8; ++nt)
      acc[nt] = __builtin_amdgcn_mfma_f32_16x16x32_bf16(caf, cbf[nt], acc[nt], 0, 0, 0);
    if (ks + 1 < 8){
      caf = naf;
      #pragma unroll
      for (int nt = 0; nt < 8; ++nt) cbf[nt] = nbf[nt];
    }
  }
  x2part += __shfl_xor(x2part, 16, 64);
  x2part += __shfl_xor(x2part, 32, 64);

  const size_t base = ((size_t)(p * 128 + rg) * 2 + kslice) * 8192;
  #pragma unroll
  for (int nt = 0; nt < 8; ++nt)
    #pragma unroll
    for (int r = 0; r < 4; ++r)
      partC[base + (size_t)(quad * 4 + r) * 512 + w * 128 + nt * 16 + col] = f2bf(acc[nt][r]);
  if (w == 0 && quad == 0)
    partX2[((size_t)(p * 128 + rg) * 2 + kslice) * 16 + col] = x2part;
}

// K1b: combine k-halves + transform + normalization tail (frozen R22).
__global__ __launch_bounds__(256) void hlin_fin_kernel(
    const unsigned short* __restrict__ partC, const float* __restrict__ partX2,
    const void* __restrict__ Bq, const void* __restrict__ Bk, const void* __restrict__ Bv,
    const float* __restrict__ znacc, const unsigned short* __restrict__ qprobe,
    unsigned short* __restrict__ qkvb, float* __restrict__ stats,
    float* __restrict__ cqs, float* __restrict__ iks,
    unsigned short* __restrict__ VT)
{
  const int p = blockIdx.y;
  const void* Bb = (p == 0) ? Bq : ((p == 1) ? Bk : Bv);
  const int rg = blockIdx.x;
  const int r0 = rg * 16;
  const int t  = threadIdx.x;
  const int w = t >> 6, lane = t & 63;
  const int col = lane & 15, quad = lane >> 4;
  const int isf32 = detect_f32(qprobe);

  __shared__ float smem[16 * EDIM];
  __shared__ float sw2[16];

  const size_t base0 = ((size_t)(p * 128 + rg) * 2 + 0) * 8192;
  const size_t base1 = base0 + 8192;

  f32x4 acc[8];
  #pragma unroll
  for (int nt = 0; nt < 8; ++nt)
    #pragma unroll
    for (int r = 0; r < 4; ++r){
      const size_t idx = (size_t)(quad * 4 + r) * 512 + w * 128 + nt * 16 + col;
      acc[nt][r] = bf2f(partC[base0 + idx]) + bf2f(partC[base1 + idx]);
    }

  float lamr[4], lm1[4];
  #pragma unroll
  for (int r = 0; r < 4; ++r){
    const int row = quad * 4 + r;
    float x2r = partX2[((size_t)(p * 128 + rg) * 2 + 0) * 16 + row] +
                partX2[((size_t)(p * 128 + rg) * 2 + 1) * 16 + row];
    lamr[r] = 2.f / (1.f - x2r);
    lm1[r] = lamr[r] - 1.f;
  }
  #pragma unroll
  for (int nt = 0; nt < 8; ++nt){
    const int n = w * 128 + nt * 16 + col;
    float zsum = 0.f;
    #pragma unroll
    for (int bi = 0; bi < 8; ++bi)
      zsum += znacc[((size_t)(bi * 3 + p)) * EDIM + n];
    float znv = fmaxf(sqrtf(zsum), EPSF);
    float rb;
    if (isf32) rb = ((const float*)Bb)[n];
    else       rb = bf2f(((const unsigned short*)Bb)[n]);
    float e2r = __expf(2.f * rb);
    float ie2r = 1.f / e2r;
    float ch = 0.5f * (e2r + ie2r), sh = 0.5f * (e2r - ie2r);
    float izn = 1.f / znv;
    float tz = 2.f * znv;
    #pragma unroll
    for (int r = 0; r < 4; ++r){
      float a = (acc[nt][r] * lamr[r] * izn) * ch - lm1[r] * sh;
      float b = a + sqrtf(a * a + 1.f);
      float tt = __expf(tz * __logf(b));
      smem[(quad * 4 + r) * EDIM + n] = 0.5f * (tt - 1.f / tt);
    }
  }
  __syncthreads();

  {
    int row = t >> 4, l = t & 15;
    float s = 0.f;
    for (int o = l; o < EDIM; o += 16){ float wv = smem[row * EDIM + o]; s += wv * wv; }
    #pragma unroll
    for (int m = 8; m >= 1; m >>= 1) s += __shfl_xor(s, m, 16);
    if (l == 0) sw2[row] = s;
  }
  __syncthreads();

  const int o0 = 2 * t;
  const int h0 = t >> 5;
  const int d0 = o0 & 63;
  const int l5 = t & 31;
  #pragma unroll
  for (int rr = 0; rr < 16; ++rr){
    float inv = 1.f / (1.f + sqrtf(1.f + sw2[rr]));
    unsigned short b0 = f2bf(smem[rr * EDIM + o0] * inv);
    unsigned short b1 = f2bf(smem[rr * EDIM + o0 + 1] * inv);
    float r0v = bf2f(b0), r1v = bf2f(b1);
    int s = r0 + rr;
    unsigned int* dst = (unsigned int*)&qkvb[(((size_t)p * H + h0) * SEQ + s) * HD + d0];
    *dst = (unsigned int)b0 | ((unsigned int)b1 << 16);
    float ss = r0v * r0v + r1v * r1v;
    #pragma unroll
    for (int m = 16; m >= 1; m >>= 1) ss += __shfl_xor(ss, m, 64);
    if (p == 2){
      float lam = 2.f / (1.f - ss);
      VT[((size_t)h0 * 80 + d0) * SEQ + s]     = f2bf(r0v * lam);
      VT[((size_t)h0 * 80 + d0 + 1) * SEQ + s] = f2bf(r1v * lam);
      if (l5 < 16)
        VT[((size_t)h0 * 80 + 64 + l5) * SEQ + s] = (l5 == 0) ? f2bf(lam - 1.f) : 0;
    }
    if (l5 == 0){
      stats[((size_t)p * H + h0) * SEQ + s] = ss;
      if (p == 0) cqs[(size_t)h0 * SEQ + s] = 2.f / (1.f - ss);
      if (p == 1) iks[(size_t)h0 * SEQ + s] = 1.f / (1.f - ss);
    }
  }
}

// K3a: attention — R21 pipelined body, but each wave now services TWO q-subtiles
// (q0 and q0+32) sharing ALL K/k2/ik/VT loads: per-pair load traffic halves and
// the two accumulator streams double in-wave ILP. Grid (32*8*2, H).
__global__ __launch_bounds__(64) void attn_kernel(
    const unsigned short* __restrict__ Qb, const unsigned short* __restrict__ Kb,
    const unsigned short* __restrict__ VT,
    const float* __restrict__ q2s_all, const float* __restrict__ k2s_all,
    const float* __restrict__ cqs_all, const float* __restrict__ iks_all,
    const void* __restrict__ tau, const void* __restrict__ gam,
    const unsigned short* __restrict__ qprobe,
    float* __restrict__ big, int use_part)
{
  const int h  = blockIdx.y;
  const int tile = 31 - (blockIdx.x >> 4);   // LPT
  const int sl = (blockIdx.x >> 1) & 7;      // k-slice
  const int wp = blockIdx.x & 1;             // q-subtile pair {wp, wp+2}
  if (sl > tile) return;
  const int lane = threadIdx.x;
  const int col = lane & 15, quad = lane >> 4;
  const int q0A = tile * 64 + wp * 16;
  const int q0B = q0A + 32;

  const unsigned short* Qh  = Qb + (size_t)h * SEQ * HD;
  const unsigned short* Kh  = Kb + (size_t)h * SEQ * HD;
  const unsigned short* VTh = VT + (size_t)h * 80 * SEQ;
  const float* q2s = q2s_all + (size_t)h * SEQ;
  const float* k2s = k2s_all + (size_t)h * SEQ;
  const float* cqs = cqs_all + (size_t)h * SEQ;
  const float* iks = iks_all + (size_t)h * SEQ;

  const int isf32 = detect_f32(qprobe);
  float tauv, gamv;
  if (isf32){ tauv = ((const float*)tau)[0]; gamv = ((const float*)gam)[0]; }
  else      { tauv = bf2f(((const unsigned short*)tau)[0]);
              gamv = bf2f(((const unsigned short*)gam)[0]); }
  const float e_tau = __expf(tauv);

  const int srcA = ((quad & 1) * 2) * 16 + col;
  const int srcB = srcA + 16;
  const int tsel = quad >> 1;

  bf16x8 qfA0 = *(const bf16x8*)&Qh[(size_t)(q0A + col) * HD + quad * 8];
  bf16x8 qfA1 = *(const bf16x8*)&Qh[(size_t)(q0A + col) * HD + 32 + quad * 8];
  bf16x8 qfB0 = *(const bf16x8*)&Qh[(size_t)(q0B + col) * HD + quad * 8];
  bf16x8 qfB1 = *(const bf16x8*)&Qh[(size_t)(q0B + col) * HD + 32 + quad * 8];
  const float q2A = q2s[q0A + col], q2B = q2s[q0B + col];
  const float cqA = cqs[q0A + col], cqB = cqs[q0B + col];
  const int qmaxA = q0A + col, qmaxB = q0B + col;

  f32x4 pvA[5], pvB[5];
  #pragma unroll
  for (int nt = 0; nt < 5; ++nt){
    pvA[nt] = (f32x4){0.f, 0.f, 0.f, 0.f};
    pvB[nt] = (f32x4){0.f, 0.f, 0.f, 0.f};
  }

  const int nch = ((tile - sl) >> 3) + 1;
  const int nhalf = nch * 2;
  int kb32 = sl * 64;

  bf16x8 ckf0[2], ckf1[2], nkf0[2], nkf1[2];
  float4 ck2[2], cik[2], nk2[2], nik[2];
  #pragma unroll
  for (int tt = 0; tt < 2; ++tt){
    const int kbase = kb32 + 16 * tt;
    ckf0[tt] = *(const bf16x8*)&Kh[(size_t)(kbase + col) * HD + quad * 8];
    ckf1[tt] = *(const bf16x8*)&Kh[(size_t)(kbase + col) * HD + 32 + quad * 8];
    ck2[tt]  = *(const float4*)&k2s[kbase + quad * 4];
    cik[tt]  = *(const float4*)&iks[kbase + quad * 4];
  }

  for (int i = 0; i < nhalf; ++i){
    const int nkb32 = (i & 1) ? (kb32 + 512 - 32) : (kb32 + 32);
    const bool have_next = (i + 1 < nhalf);
    if (have_next){
      #pragma unroll
      for (int tt = 0; tt < 2; ++tt){
        const int kbase = nkb32 + 16 * tt;
        nkf0[tt] = *(const bf16x8*)&Kh[(size_t)(kbase + col) * HD + quad * 8];
        nkf1[tt] = *(const bf16x8*)&Kh[(size_t)(kbase + col) * HD + 32 + quad * 8];
        nk2[tt]  = *(const float4*)&k2s[kbase + quad * 4];
        nik[tt]  = *(const float4*)&iks[kbase + quad * 4];
      }
    }

    unsigned int tloA[2], thiA[2], tloB[2], thiB[2];
    #pragma unroll
    for (int tt = 0; tt < 2; ++tt){
      const int kbase = kb32 + 16 * tt;
      f32x4 sA = (f32x4){0.f, 0.f, 0.f, 0.f};
      f32x4 sB = (f32x4){0.f, 0.f, 0.f, 0.f};
      sA = __builtin_amdgcn_mfma_f32_16x16x32_bf16(ckf0[tt], qfA0, sA, 0, 0, 0);
      sB = __builtin_amdgcn_mfma_f32_16x16x32_bf16(ckf0[tt], qfB0, sB, 0, 0, 0);
      sA = __builtin_amdgcn_mfma_f32_16x16x32_bf16(ckf1[tt], qfA1, sA, 0, 0, 0);
      sB = __builtin_amdgcn_mfma_f32_16x16x32_bf16(ckf1[tt], qfB1, sB, 0, 0, 0);
      unsigned short pbA[4], pbB[4];
      #pragma unroll
      for (int r = 0; r < 4; ++r){
        float k2 = (r == 0) ? ck2[tt].x : (r == 1) ? ck2[tt].y : (r == 2) ? ck2[tt].z : ck2[tt].w;
        float ik = (r == 0) ? cik[tt].x : (r == 1) ? cik[tt].y : (r == 2) ? cik[tt].z : cik[tt].w;
        const int key = kbase + quad * 4 + r;
        // stream A
        {
          float diff2 = fmaxf(q2A + k2 - 2.f * sA[r], 0.f);
          float u = fmaxf(diff2 * cqA * ik, 1e-7f);
          float z = 1.f + u + sqrtf(u * (u + 2.f));
          float wv = __expf(-e_tau * __logf(z) - gamv);
          if (key > qmaxA) wv = 0.f;
          pbA[r] = f2bf(wv);
        }
        // stream B
        {
          float diff2 = fmaxf(q2B + k2 - 2.f * sB[r], 0.f);
          float u = fmaxf(diff2 * cqB * ik, 1e-7f);
          float z = 1.f + u + sqrtf(u * (u + 2.f));
          float wv = __expf(-e_tau * __logf(z) - gamv);
          if (key > qmaxB) wv = 0.f;
          pbB[r] = f2bf(wv);
        }
      }
      tloA[tt] = (unsigned int)pbA[0] | ((unsigned int)pbA[1] << 16);
      thiA[tt] = (unsigned int)pbA[2] | ((unsigned int)pbA[3] << 16);
      tloB[tt] = (unsigned int)pbB[0] | ((unsigned int)pbB[1] << 16);
      thiB[tt] = (unsigned int)pbB[2] | ((unsigned int)pbB[3] << 16);
    }
    // transpose both streams
    union { uint4 u; bf16x8 v; } pwA, pwB;
    {
      unsigned int a0 = (unsigned int)__shfl((int)tloA[0], srcA, 64);
      unsigned int a1 = (unsigned int)__shfl((int)tloA[1], srcA, 64);
      unsigned int b0 = (unsigned int)__shfl((int)thiA[0], srcA, 64);
      unsigned int b1 = (unsigned int)__shfl((int)thiA[1], srcA, 64);
      unsigned int c0 = (unsigned int)__shfl((int)tloA[0], srcB, 64);
      unsigned int c1 = (unsigned int)__shfl((int)tloA[1], srcB, 64);
      unsigned int d0 = (unsigned int)__shfl((int)thiA[0], srcB, 64);
      unsigned int d1 = (unsigned int)__shfl((int)thiA[1], srcB, 64);
      pwA.u.x = tsel ? a1 : a0;
      pwA.u.y = tsel ? b1 : b0;
      pwA.u.z = tsel ? c1 : c0;
      pwA.u.w = tsel ? d1 : d0;
    }
    {
      unsigned int a0 = (unsigned int)__shfl((int)tloB[0], srcA, 64);
      unsigned int a1 = (unsigned int)__shfl((int)tloB[1], srcA, 64);
      unsigned int b0 = (unsigned int)__shfl((int)thiB[0], srcA, 64);
      unsigned int b1 = (unsigned int)__shfl((int)thiB[1], srcA, 64);
      unsigned int c0 = (unsigned int)__shfl((int)tloB[0], srcB, 64);
      unsigned int c1 = (unsigned int)__shfl((int)tloB[1], srcB, 64);
      unsigned int d0 = (unsigned int)__shfl((int)thiB[0], srcB, 64);
      unsigned int d1 = (unsigned int)__shfl((int)thiB[1], srcB, 64);
      pwB.u.x = tsel ? a1 : a0;
      pwB.u.y = tsel ? b1 : b0;
      pwB.u.z = tsel ? c1 : c0;
      pwB.u.w = tsel ? d1 : d0;
    }
    // PV: vf loaded ONCE, feeds both streams
    #pragma unroll
    for (int nt = 0; nt < 5; ++nt){
      bf16x8 vf = *(const bf16x8*)&VTh[(size_t)(16 * nt + col) * SEQ + kb32 + quad * 8];
      pvA[nt] = __builtin_amdgcn_mfma_f32_16x16x32_bf16(pwA.v, vf, pvA[nt], 0, 0, 0);
      pvB[nt] = __builtin_amdgcn_mfma_f32_16x16x32_bf16(pwB.v, vf, pvB[nt], 0, 0, 0);
    }

    if (have_next){
      #pragma unroll
      for (int tt = 0; tt < 2; ++tt){
        ckf0[tt] = nkf0[tt]; ckf1[tt] = nkf1[tt];
        ck2[tt] = nk2[tt];   cik[tt] = nik[tt];
      }
    }
    kb32 = nkb32;
  }

  if (use_part){
    uint2* slotA = (uint2*)big + (size_t)((((h * 32 + tile) * 8) + sl) * 4 + wp) * 320;
    uint2* slotB = (uint2*)big + (size_t)((((h * 32 + tile) * 8) + sl) * 4 + wp + 2) * 320;
    #pragma unroll
    for (int nt = 0; nt < 5; ++nt){
      uint2 pk;
      pk.x = (unsigned int)f2bf(pvA[nt][0]) | ((unsigned int)f2bf(pvA[nt][1]) << 16);
      pk.y = (unsigned int)f2bf(pvA[nt][2]) | ((unsigned int)f2bf(pvA[nt][3]) << 16);
      slotA[nt * 64 + lane] = pk;
      pk.x = (unsigned int)f2bf(pvB[nt][0]) | ((unsigned int)f2bf(pvB[nt][1]) << 16);
      pk.y = (unsigned int)f2bf(pvB[nt][2]) | ((unsigned int)f2bf(pvB[nt][3]) << 16);
      slotB[nt * 64 + lane] = pk;
    }
  } else {
    #pragma unroll
    for (int r = 0; r < 4; ++r){
      float* rowA = big + ((size_t)h * SEQ + q0A + quad * 4 + r) * 80;
      float* rowB = big + ((size_t)h * SEQ + q0B + quad * 4 + r) * 80;
      #pragma unroll
      for (int nt = 0; nt < 5; ++nt){
        atomicAdd(&rowA[16 * nt + col], pvA[nt][r]);
        atomicAdd(&rowB[16 * nt + col], pvB[nt][r]);
      }
    }
  }
}

// K3b: bf16-slice-sum + LDS reduce + gyromidpoint (frozen). Grid (128, H), 256 thr.
__global__ __launch_bounds__(256) void attn_fin_kernel(
    const float* __restrict__ big, int use_part,
    float* __restrict__ out, float beta_scale)
{
  const int h = blockIdx.y, tile16 = blockIdx.x;
  const int t = threadIdx.x;
  const int w = t >> 6, lane = t & 63;
  const int col = lane & 15, quad = lane >> 4;
  const int q0 = tile16 * 16;

  __shared__ float red[4][64][20];

  f32x4 pv[5];
  #pragma unroll
  for (int nt = 0; nt < 5; ++nt) pv[nt] = (f32x4){0.f, 0.f, 0.f, 0.f};

  if (use_part){
    const int st = tile16 >> 2, wq = tile16 & 3;
    const int nv = (st + 1 < 8) ? st + 1 : 8;
    for (int sl = w; sl < nv; sl += 4){
      const uint2* slot = (const uint2*)big +
          (size_t)((((h * 32 + st) * 8) + sl) * 4 + wq) * 320;
      #pragma unroll
      for (int nt = 0; nt < 5; ++nt){
        uint2 v = slot[nt * 64 + lane];
        pv[nt][0] += bf2f((unsigned short)(v.x & 0xffffu));
        pv[nt][1] += bf2f((unsigned short)(v.x >> 16));
        pv[nt][2] += bf2f((unsigned short)(v.y & 0xffffu));
        pv[nt][3] += bf2f((unsigned short)(v.y >> 16));
      }
    }
  } else if (w == 0){
    #pragma unroll
    for (int nt = 0; nt < 5; ++nt)
      #pragma unroll
      for (int r = 0; r < 4; ++r)
        pv[nt][r] = big[((size_t)h * SEQ + q0 + quad * 4 + r) * 80 + 16 * nt + col];
  }

  #pragma unroll
  for (int nt = 0; nt < 5; ++nt)
    *(float4*)&red[w][lane][nt * 4] = (float4){pv[nt][0], pv[nt][1], pv[nt][2], pv[nt][3]};
  __syncthreads();

  if (t < 64){
    #pragma unroll
    for (int nt = 0; nt < 5; ++nt){
      float4 a = *(const float4*)&red[0][t][nt * 4];
      float4 b = *(const float4*)&red[1][t][nt * 4];
      float4 c = *(const float4*)&red[2][t][nt * 4];
      float4 d = *(const float4*)&red[3][t][nt * 4];
      pv[nt][0] = a.x + b.x + c.x + d.x;
      pv[nt][1] = a.y + b.y + c.y + d.y;
      pv[nt][2] = a.z + b.z + c.z + d.z;
      pv[nt][3] = a.w + b.w + c.w + d.w;
    }
    #pragma unroll
    for (int r = 0; r < 4; ++r){
      float den = __shfl(pv[4][r], quad * 16, 64);
      den = fmaxf(den, EPSF);
      float inv_den = 1.f / den;
      float g[4];
      float gsq = 0.f;
      #pragma unroll
      for (int nt = 0; nt < 4; ++nt){ g[nt] = pv[nt][r] * inv_den; gsq += g[nt] * g[nt]; }
      #pragma unroll
      for (int m = 8; m >= 1; m >>= 1) gsq += __shfl_xor(gsq, m, 64);
      float gn = fmaxf(sqrtf(gsq), EPSF);
      float x = fminf(gn, 1.f - 1e-7f);
      float tt2 = x / (1.f + sqrtf(1.f - x * x));
      float scl = (tt2 / gn) * beta_scale;
      const int q = q0 + quad * 4 + r;
      #pragma unroll
      for (int nt = 0; nt < 4; ++nt)
        out[(size_t)q * EDIM + h * HD + 16 * nt + col] = g[nt] * scl;
    }
  }
}

extern "C" void kernel_launch(void* const* d_in, const int* in_sizes, int n_in,
                              void* d_out, int out_size, void* d_ws, size_t ws_size,
                              hipStream_t stream){
  const void* Xq  = d_in[0];
  const void* Xk  = d_in[1];
  const void* Xv  = d_in[2];
  const void* Wq  = d_in[3];
  const void* Wk  = d_in[4];
  const void* Wv  = d_in[5];
  const void* Bq  = d_in[6];
  const void* Bk  = d_in[7];
  const void* Bv  = d_in[8];
  const void* tau = d_in[9];
  const void* gam = d_in[10];

  float* wsf   = (float*)d_ws;
  float* zn    = wsf + ZN_OFF;
  float* stats = wsf + STATS_OFF;
  float* cqs   = wsf + CQ_OFF;
  float* iks   = wsf + IK_OFF;
  float* px2   = wsf + PX2_OFF;
  unsigned short* u16b = (unsigned short*)(wsf + U16_OFF);
  unsigned short* WT   = u16b + WT_U16;
  unsigned short* qkvb = u16b + QKVB_U16;
  unsigned short* VT   = u16b + VT_U16;
  float* big   = wsf + BIG_OFF;
  unsigned short* partC = (unsigned short*)big;   // reused before attn runs

  const int use_part =
      (ws_size >= (size_t)BIG_OFF * sizeof(float) + (size_t)PART_U16S * 2) ? 1 : 0;

  unsigned short* Qb = qkvb;
  unsigned short* Kb = qkvb + (size_t)H * SEQ * HD;
  float* q2s = stats;
  float* k2s = stats + (size_t)H * SEQ;
  const unsigned short* qprobe = (const unsigned short*)Xq;

  double lb1 = lgamma(EDIM / 2.0) + lgamma(0.5) - lgamma(EDIM / 2.0 + 0.5);
  double lb2 = lgamma(HD / 2.0)   + lgamma(0.5) - lgamma(HD / 2.0 + 0.5);
  float beta_scale = (float)exp(lb1 - lb2);

  wcvt_kernel<<<dim3(64, 3), dim3(256), 0, stream>>>(Wq, Wk, Wv, qprobe, WT, zn);
  hlin_gemm_kernel<<<dim3(256, 3), dim3(256), 0, stream>>>(
      Xq, Xk, Xv, WT, qprobe, partC, px2);
  hlin_fin_kernel<<<dim3(128, 3), dim3(256), 0, stream>>>(
      partC, px2, Bq, Bk, Bv, zn, qprobe, qkvb, stats, cqs, iks, VT);
  if (!use_part)
    hipMemsetAsync(big, 0, (size_t)ACC_FLOATS * sizeof(float), stream);
  attn_kernel<<<dim3(32 * 8 * 2, H), dim3(64), 0, stream>>>(
      Qb, Kb, VT, q2s, k2s, cqs, iks, tau, gam, qprobe, big, use_part);
  attn_fin_kernel<<<dim3(128, H), dim3(256), 0, stream>>>(
      big, use_part, (float*)d_out, beta_scale);
}